// Round 1
// baseline (655.773 us; speedup 1.0000x reference)
//
#include <hip/hip_runtime.h>

#define BGR 32768
#define NNODE 19
#define NTOT (BGR*NNODE)       // 622592
#define EF 120
#define ES 60
#define NB 5
#define EPS 1e-5f

// ---- workspace layout (float offsets) ----
#define WS_U     0                         // NTOT*NB      = 3,112,960
#define WS_PRE2  (WS_U + NTOT*NB)          // BGR*190      = 6,225,920 (xc in-place)
#define WS_PRE3  (WS_PRE2 + BGR*190)       // BGR*128      = 4,194,304
#define WS_P1    (WS_PRE3 + BGR*128)       // BGR*10
#define WS_P2    (WS_P1 + BGR*10)          // BGR*20
#define WS_P3    (WS_P2 + BGR*20)          // 2048*256
#define WS_R1    (WS_P3 + 2048*256)        // 64*10
#define WS_R2    (WS_R1 + 64*10)           // 64*20
#define WS_R3    (WS_R2 + 64*20)           // 64*256
#define WS_A1    (WS_R3 + 64*256)          // 160
#define WS_D1    (WS_A1 + 160)             // 160
#define WS_A2    (WS_D1 + 160)             // 10
#define WS_D2    (WS_A2 + 10)              // 10
#define WS_A3    (WS_D2 + 10)              // 128
#define WS_D3    (WS_A3 + 128)             // 128

// ---------------- K1: GCN1 reduced to scalar u per (node,band) ----------------
__global__ __launch_bounds__(64) void k1_gcn1(
    const float* __restrict__ x, const float* __restrict__ ew,
    const int* __restrict__ srcf, const int* __restrict__ dstf,
    float* __restrict__ u, float* __restrict__ p1)
{
    __shared__ float xg[NB][NNODE];
    __shared__ float deg[NNODE];
    __shared__ float dinv[NNODE];
    __shared__ float z[NB][NNODE];
    __shared__ float ps[2*NB];
    int g = blockIdx.x, t = threadIdx.x;

    if (t < NNODE) deg[t] = 0.f;
    for (int i = t; i < NB*NNODE; i += 64) ((float*)z)[i] = 0.f;
    if (t < 2*NB) ps[t] = 0.f;
    for (int i = t; i < NNODE*NB; i += 64) {
        int v = i / NB, b = i % NB;
        xg[b][v] = x[g*NNODE*NB + i];
    }
    __syncthreads();

    int s0=0,d0=0,s1=0,d1=0; float w0=0.f,w1=0.f;
    bool e0 = (t < EF), e1 = (t+64 < EF);
    if (e0) {
        s0 = srcf[g*EF+t]    - g*NNODE; d0 = dstf[g*EF+t]    - g*NNODE; w0 = ew[g*EF+t];
        atomicAdd(&deg[d0], w0);
    }
    if (e1) {
        s1 = srcf[g*EF+t+64] - g*NNODE; d1 = dstf[g*EF+t+64] - g*NNODE; w1 = ew[g*EF+t+64];
        atomicAdd(&deg[d1], w1);
    }
    __syncthreads();
    if (t < NNODE) dinv[t] = rsqrtf(deg[t] + 1.f);
    __syncthreads();
    if (e0) {
        float nm = dinv[s0]*w0*dinv[d0];
        #pragma unroll
        for (int b=0;b<NB;b++) atomicAdd(&z[b][d0], nm*xg[b][s0]);
    }
    if (e1) {
        float nm = dinv[s1]*w1*dinv[d1];
        #pragma unroll
        for (int b=0;b<NB;b++) atomicAdd(&z[b][d1], nm*xg[b][s1]);
    }
    __syncthreads();
    for (int i = t; i < NNODE*NB; i += 64) {
        int v = i / NB, b = i % NB;
        float di = dinv[v];
        float uv = z[b][v] + di*di*xg[b][v];
        u[g*NNODE*NB + i] = uv;
        atomicAdd(&ps[b], uv);
        atomicAdd(&ps[NB+b], uv*uv);
    }
    __syncthreads();
    if (t < 2*NB) p1[g*10 + t] = ps[t];
}

// ---------------- generic column reducer: rows x COLS -> gridDim x COLS ----------------
template<int COLS>
__global__ __launch_bounds__(256) void k_colreduce(
    const float* __restrict__ in, float* __restrict__ out, int rows)
{
    int j = blockIdx.x;
    int chunk = (rows + gridDim.x - 1) / gridDim.x;
    int r0 = j*chunk, r1 = min(rows, r0+chunk);
    float acc[COLS];
    #pragma unroll
    for (int k=0;k<COLS;k++) acc[k]=0.f;
    for (int r = r0 + (int)threadIdx.x; r < r1; r += 256) {
        #pragma unroll
        for (int k=0;k<COLS;k++) acc[k] += in[r*COLS+k];
    }
    __shared__ float red[256][COLS];
    #pragma unroll
    for (int k=0;k<COLS;k++) red[threadIdx.x][k] = acc[k];
    __syncthreads();
    for (int off=128; off>0; off>>=1) {
        if ((int)threadIdx.x < off) {
            #pragma unroll
            for (int k=0;k<COLS;k++) red[threadIdx.x][k] += red[threadIdx.x+off][k];
        }
        __syncthreads();
    }
    if (threadIdx.x == 0) {
        #pragma unroll
        for (int k=0;k<COLS;k++) out[j*COLS+k] = red[0][k];
    }
}

// ---------------- K2b: finalize BN1 stats -> affine A1,D1 ----------------
__global__ __launch_bounds__(256) void k2b(const float* __restrict__ r1,
    const float* __restrict__ W1, const float* __restrict__ g1, const float* __restrict__ bt1,
    float* __restrict__ A1, float* __restrict__ D1)
{
    __shared__ float ssum[10], mean[5], varr[5];
    int t = threadIdx.x;
    if (t < 10) { float s=0.f; for (int j=0;j<64;j++) s += r1[j*10+t]; ssum[t]=s; }
    __syncthreads();
    if (t < 5) {
        float m = ssum[t] / (float)NTOT;
        mean[t] = m;
        varr[t] = ssum[5+t] / (float)NTOT - m*m;
    }
    __syncthreads();
    if (t < 160) {
        int b = t >> 5;
        float w = W1[t];
        float c = w * rsqrtf(w*w*varr[b] + EPS) * g1[t];
        A1[t] = c;
        D1[t] = bt1[t] - c*mean[b];
    }
}

// ---------------- K3: BN1-affine+relu, 32-wide hidden, GCN2 (struct edges) ----------------
__global__ __launch_bounds__(64) void k3_gcn2(
    const float* __restrict__ u, const int* __restrict__ srcs, const int* __restrict__ dsts,
    const float* __restrict__ A1, const float* __restrict__ D1,
    const float* __restrict__ W2, const float* __restrict__ b2,
    float* __restrict__ pre2, float* __restrict__ p2)
{
    __shared__ float ug[NB][NNODE];
    __shared__ float degs[NNODE], dinvs[NNODE];
    __shared__ float h2[NB][NNODE][2];
    __shared__ float agg[NB][NNODE][2];
    __shared__ float A1l[160], D1l[160], W2l[320], b2l[10];
    __shared__ float ps[20];
    int g = blockIdx.x, t = threadIdx.x;

    for (int i=t;i<160;i+=64){ A1l[i]=A1[i]; D1l[i]=D1[i]; }
    for (int i=t;i<320;i+=64) W2l[i]=W2[i];
    if (t<10) b2l[t]=b2[t];
    if (t<20) ps[t]=0.f;
    if (t<NNODE) degs[t]=0.f;
    for (int i=t;i<NB*NNODE*2;i+=64) ((float*)agg)[i]=0.f;
    for (int i=t;i<NNODE*NB;i+=64) ug[i%NB][i/NB] = u[g*NNODE*NB+i];
    __syncthreads();

    int ls=0, ld=0;
    bool ee = (t < ES);
    if (ee) {
        ls = srcs[g*ES+t] - g*NNODE; ld = dsts[g*ES+t] - g*NNODE;
        atomicAdd(&degs[ld], 1.f);
    }
    __syncthreads();
    if (t<NNODE) dinvs[t] = rsqrtf(degs[t]+1.f);
    __syncthreads();

    for (int i=t;i<NNODE*NB;i+=64) {
        int v=i/NB, b=i%NB;
        float uv = ug[b][v];
        float h0=0.f, h1=0.f;
        #pragma unroll
        for (int f=0;f<32;f++) {
            float r = fmaxf(fmaf(A1l[b*32+f], uv, D1l[b*32+f]), 0.f);
            h0 = fmaf(r, W2l[b*64+f*2+0], h0);
            h1 = fmaf(r, W2l[b*64+f*2+1], h1);
        }
        h2[b][v][0]=h0; h2[b][v][1]=h1;
    }
    __syncthreads();
    if (ee) {
        float nm = dinvs[ls]*dinvs[ld];
        #pragma unroll
        for (int b=0;b<NB;b++) {
            atomicAdd(&agg[b][ld][0], nm*h2[b][ls][0]);
            atomicAdd(&agg[b][ld][1], nm*h2[b][ls][1]);
        }
    }
    __syncthreads();
    for (int i=t;i<NNODE*NB;i+=64) {
        int v=i/NB, b=i%NB;
        float dd = dinvs[v]*dinvs[v];
        #pragma unroll
        for (int k=0;k<2;k++) {
            float o = agg[b][v][k] + dd*h2[b][v][k] + b2l[b*2+k];
            pre2[g*190 + b*38 + v*2 + k] = o;
            atomicAdd(&ps[b*2+k], o);
            atomicAdd(&ps[10+b*2+k], o*o);
        }
    }
    __syncthreads();
    if (t<20) p2[g*20+t] = ps[t];
}

// ---------------- K4b: finalize BN2 stats -> affine A2,D2 ----------------
__global__ __launch_bounds__(64) void k4b(const float* __restrict__ r2,
    const float* __restrict__ g2, const float* __restrict__ bt2,
    float* __restrict__ A2, float* __restrict__ D2)
{
    __shared__ float ssum[20];
    int t = threadIdx.x;
    if (t < 20) { float s=0.f; for (int j=0;j<64;j++) s += r2[j*20+t]; ssum[t]=s; }
    __syncthreads();
    if (t < 10) {
        float m = ssum[t] / (float)NTOT;
        float v = ssum[10+t] / (float)NTOT - m*m;
        float a = g2[t] * rsqrtf(v + EPS);
        A2[t] = a;
        D2[t] = bt2[t] - a*m;
    }
}

// ---------------- K4x: xc = relu(A2*pre2 + D2) in place ----------------
__global__ __launch_bounds__(256) void k4x_xc(float* __restrict__ pre2,
    const float* __restrict__ A2, const float* __restrict__ D2)
{
    __shared__ float a2[10], d2[10];
    if (threadIdx.x < 10) { a2[threadIdx.x]=A2[threadIdx.x]; d2[threadIdx.x]=D2[threadIdx.x]; }
    __syncthreads();
    const int total = BGR*95;
    for (int i = blockIdx.x*256 + threadIdx.x; i < total; i += gridDim.x*256) {
        int pp = i % 95;
        int b = pp / 19;           // pairs never straddle a band (38 even)
        float2 v = ((float2*)pre2)[i];
        v.x = fmaxf(fmaf(a2[b*2+0], v.x, d2[b*2+0]), 0.f);
        v.y = fmaxf(fmaf(a2[b*2+1], v.y, d2[b*2+1]), 0.f);
        ((float2*)pre2)[i] = v;
    }
}

// ---------------- K5: pre3 = xc @ lin1_W + b (thread=feature, 16 graphs/block) ----------------
__global__ __launch_bounds__(128) void k5_lin1(
    const float* __restrict__ xc, const float* __restrict__ W, const float* __restrict__ bias,
    float* __restrict__ pre3, float* __restrict__ p3)
{
    int bid = blockIdx.x, f = threadIdx.x;
    const float* xcb = xc + bid*16*190;   // wave-uniform base
    float acc[16];
    #pragma unroll
    for (int r=0;r<16;r++) acc[r]=0.f;
    for (int k=0;k<190;k++) {
        float w = W[k*128+f];
        #pragma unroll
        for (int r=0;r<16;r++) acc[r] = fmaf(xcb[r*190+k], w, acc[r]);  // uniform loads
    }
    float bb = bias[f];
    float s=0.f, s2=0.f;
    #pragma unroll
    for (int r=0;r<16;r++) {
        float p = acc[r]+bb;
        pre3[(bid*16+r)*128+f] = p;
        s += p; s2 += p*p;
    }
    p3[bid*256+f]     = s;
    p3[bid*256+128+f] = s2;
}

// ---------------- K6a/K6b: BN3 stats reduction -> affine A3,D3 ----------------
__global__ __launch_bounds__(256) void k6a(const float* __restrict__ p3, float* __restrict__ r3)
{
    int j = blockIdx.x, f = threadIdx.x;
    float s = 0.f;
    for (int r = j*32; r < (j+1)*32; r++) s += p3[r*256+f];
    r3[j*256+f] = s;
}

__global__ __launch_bounds__(128) void k6b(const float* __restrict__ r3,
    const float* __restrict__ g3, const float* __restrict__ bt3,
    float* __restrict__ A3, float* __restrict__ D3)
{
    int f = threadIdx.x;
    float s=0.f, q=0.f;
    for (int j=0;j<64;j++) { s += r3[j*256+f]; q += r3[j*256+128+f]; }
    float m = s / (float)BGR;
    float v = q / (float)BGR - m*m;
    float a = g3[f] * rsqrtf(v + EPS);
    A3[f] = a;
    D3[f] = bt3[f] - a*m;
}

// ---------------- K7: out = relu(relu(BN3(pre3)) @ W2 + b2) @ W3 + b3, thread per graph ----------------
__global__ __launch_bounds__(256) void k7_head(
    const float* __restrict__ pre3, const float* __restrict__ A3, const float* __restrict__ D3,
    const float* __restrict__ W2h, const float* __restrict__ b2h,
    const float* __restrict__ W3h, const float* __restrict__ b3h,
    float* __restrict__ out)
{
    int g = blockIdx.x*256 + threadIdx.x;
    float accj[32];
    #pragma unroll
    for (int j=0;j<32;j++) accj[j] = b2h[j];
    const float* p3 = pre3 + g*128;
    #pragma unroll 2
    for (int f4=0; f4<128; f4+=4) {
        float4 pv = *(const float4*)(p3 + f4);
        float y0 = fmaxf(fmaf(A3[f4+0], pv.x, D3[f4+0]), 0.f);
        float y1 = fmaxf(fmaf(A3[f4+1], pv.y, D3[f4+1]), 0.f);
        float y2 = fmaxf(fmaf(A3[f4+2], pv.z, D3[f4+2]), 0.f);
        float y3 = fmaxf(fmaf(A3[f4+3], pv.w, D3[f4+3]), 0.f);
        #pragma unroll
        for (int j=0;j<32;j++) {
            accj[j] = fmaf(y0, W2h[(f4+0)*32+j], accj[j]);
            accj[j] = fmaf(y1, W2h[(f4+1)*32+j], accj[j]);
            accj[j] = fmaf(y2, W2h[(f4+2)*32+j], accj[j]);
            accj[j] = fmaf(y3, W2h[(f4+3)*32+j], accj[j]);
        }
    }
    float o0 = b3h[0], o1 = b3h[1];
    #pragma unroll
    for (int j=0;j<32;j++) {
        float yj = fmaxf(accj[j], 0.f);
        o0 = fmaf(yj, W3h[j*2+0], o0);
        o1 = fmaf(yj, W3h[j*2+1], o1);
    }
    ((float2*)out)[g] = make_float2(o0, o1);
}

extern "C" void kernel_launch(void* const* d_in, const int* in_sizes, int n_in,
                              void* d_out, int out_size, void* d_ws, size_t ws_size,
                              hipStream_t stream)
{
    (void)in_sizes; (void)n_in; (void)out_size; (void)ws_size;
    const float* x    = (const float*)d_in[0];
    const float* ew   = (const float*)d_in[1];
    const int*   eif  = (const int*)d_in[2];
    const int*   eis  = (const int*)d_in[3];
    const float* W1   = (const float*)d_in[4];
    // d_in[5] = b1: cancels exactly inside BN1 (mean subtraction) — unused
    const float* g1   = (const float*)d_in[6];
    const float* bt1  = (const float*)d_in[7];
    const float* W2   = (const float*)d_in[8];
    const float* b2   = (const float*)d_in[9];
    const float* g2   = (const float*)d_in[10];
    const float* bt2  = (const float*)d_in[11];
    const float* l1W  = (const float*)d_in[12];
    const float* l1b  = (const float*)d_in[13];
    const float* g3   = (const float*)d_in[14];
    const float* bt3  = (const float*)d_in[15];
    const float* l2W  = (const float*)d_in[16];
    const float* l2b  = (const float*)d_in[17];
    const float* l3W  = (const float*)d_in[18];
    const float* l3b  = (const float*)d_in[19];
    float* out = (float*)d_out;
    float* ws  = (float*)d_ws;

    const int* srcf = eif;  const int* dstf = eif + BGR*EF;
    const int* srcs = eis;  const int* dsts = eis + BGR*ES;

    float* U    = ws + WS_U;
    float* PRE2 = ws + WS_PRE2;
    float* PRE3 = ws + WS_PRE3;
    float* P1   = ws + WS_P1;
    float* P2   = ws + WS_P2;
    float* P3   = ws + WS_P3;
    float* R1   = ws + WS_R1;
    float* R2   = ws + WS_R2;
    float* R3   = ws + WS_R3;
    float* A1   = ws + WS_A1;
    float* D1   = ws + WS_D1;
    float* A2   = ws + WS_A2;
    float* D2   = ws + WS_D2;
    float* A3   = ws + WS_A3;
    float* D3   = ws + WS_D3;

    k1_gcn1<<<BGR, 64, 0, stream>>>(x, ew, srcf, dstf, U, P1);
    k_colreduce<10><<<64, 256, 0, stream>>>(P1, R1, BGR);
    k2b<<<1, 256, 0, stream>>>(R1, W1, g1, bt1, A1, D1);
    k3_gcn2<<<BGR, 64, 0, stream>>>(U, srcs, dsts, A1, D1, W2, b2, PRE2, P2);
    k_colreduce<20><<<64, 256, 0, stream>>>(P2, R2, BGR);
    k4b<<<1, 64, 0, stream>>>(R2, g2, bt2, A2, D2);
    k4x_xc<<<2048, 256, 0, stream>>>(PRE2, A2, D2);
    k5_lin1<<<2048, 128, 0, stream>>>(PRE2, l1W, l1b, PRE3, P3);
    k6a<<<64, 256, 0, stream>>>(P3, R3);
    k6b<<<1, 128, 0, stream>>>(R3, g3, bt3, A3, D3);
    k7_head<<<BGR/256, 256, 0, stream>>>(PRE3, A3, D3, l2W, l2b, l3W, l3b, out);
}

// Round 2
// 576.072 us; speedup vs baseline: 1.1384x; 1.1384x over previous
//
#include <hip/hip_runtime.h>

#define BGR 32768
#define NNODE 19
#define NTOT (BGR*NNODE)       // 622592
#define EF 120
#define ES 60
#define NB 5
#define EPS 1e-5f

// ---- workspace layout (float offsets) ----
#define WS_U     0                          // NTOT*NB  = 3,112,960
#define WS_PRE2  (WS_U + NTOT*NB)           // BGR*190  = 6,225,920 (xc in-place)
#define WS_PRE3  (WS_PRE2 + BGR*190)        // BGR*128  = 4,194,304
#define WS_R1    (WS_PRE3 + BGR*128)        // 64*10
#define WS_R2    (WS_R1 + 640)              // 64*20
#define WS_P3    (WS_R2 + 1280)             // 2048*256
#define WS_R3    (WS_P3 + 2048*256)         // 64*256
#define WS_T1    (WS_R3 + 64*256)           // 5*33*4 = 660 (float4-aligned offset)
#define WS_A2    (WS_T1 + 660)              // 10
#define WS_D2    (WS_A2 + 10)               // 10
#define WS_A3    (WS_D2 + 10)               // 128
#define WS_D3    (WS_A3 + 128)              // 128

// ---------------- K1: GCN1 reduced to scalar u per (node,band) ----------------
__global__ __launch_bounds__(64) void k1_gcn1(
    const float* __restrict__ x, const float* __restrict__ ew,
    const int* __restrict__ srcf, const int* __restrict__ dstf,
    float* __restrict__ u)
{
    __shared__ float xg[NB][NNODE];
    __shared__ float deg[NNODE];
    __shared__ float dinv[NNODE];
    __shared__ float z[NB][NNODE];   // z[b][v]: banks (19b+v)%32 distinct per b
    int g = blockIdx.x, t = threadIdx.x;

    if (t < NNODE) deg[t] = 0.f;
    for (int i = t; i < NB*NNODE; i += 64) ((float*)z)[i] = 0.f;
    for (int i = t; i < NNODE*NB; i += 64) {
        int v = i / NB, b = i % NB;
        xg[b][v] = x[g*NNODE*NB + i];
    }
    __syncthreads();

    int s0=0,d0=0,s1=0,d1=0; float w0=0.f,w1=0.f;
    bool e0 = (t < EF), e1 = (t+64 < EF);
    if (e0) {
        s0 = srcf[g*EF+t]    - g*NNODE; d0 = dstf[g*EF+t]    - g*NNODE; w0 = ew[g*EF+t];
        atomicAdd(&deg[d0], w0);
    }
    if (e1) {
        s1 = srcf[g*EF+t+64] - g*NNODE; d1 = dstf[g*EF+t+64] - g*NNODE; w1 = ew[g*EF+t+64];
        atomicAdd(&deg[d1], w1);
    }
    __syncthreads();
    if (t < NNODE) dinv[t] = rsqrtf(deg[t] + 1.f);
    __syncthreads();
    if (e0) {
        float nm = dinv[s0]*w0*dinv[d0];
        #pragma unroll
        for (int b=0;b<NB;b++) atomicAdd(&z[b][d0], nm*xg[b][s0]);
    }
    if (e1) {
        float nm = dinv[s1]*w1*dinv[d1];
        #pragma unroll
        for (int b=0;b<NB;b++) atomicAdd(&z[b][d1], nm*xg[b][s1]);
    }
    __syncthreads();
    for (int i = t; i < NNODE*NB; i += 64) {
        int v = i / NB, b = i % NB;
        float di = dinv[v];
        u[g*NNODE*NB + i] = z[b][v] + di*di*xg[b][v];
    }
}

// ---------------- KR1: per-band sum & sumsq over U ----------------
__global__ __launch_bounds__(256) void kr1(const float* __restrict__ U, float* __restrict__ r1)
{
    int j = blockIdx.x;                    // 64 blocks
    const int CH = NTOT*NB/64;             // 48640, divisible by 5
    const float* base = U + j*CH;
    float s[5], q[5];
    #pragma unroll
    for (int b=0;b<5;b++){ s[b]=0.f; q[b]=0.f; }
    #pragma unroll
    for (int b=0;b<5;b++) {
        for (int m = threadIdx.x; m < CH/5; m += 256) {
            float v = base[5*m + b];       // global idx %5 == b  (band)
            s[b]+=v; q[b]+=v*v;
        }
    }
    __shared__ float red[256][10];
    #pragma unroll
    for (int b=0;b<5;b++){ red[threadIdx.x][b]=s[b]; red[threadIdx.x][5+b]=q[b]; }
    __syncthreads();
    for (int off=128; off>0; off>>=1) {
        if ((int)threadIdx.x < off) {
            #pragma unroll
            for (int k=0;k<10;k++) red[threadIdx.x][k] += red[threadIdx.x+off][k];
        }
        __syncthreads();
    }
    if (threadIdx.x < 10) r1[j*10 + threadIdx.x] = red[0][threadIdx.x];
}

// ---------------- K2b: BN1 stats -> packed padded table T1[b][33] = (A1,D1,W2_0,W2_1) ----------------
__global__ __launch_bounds__(256) void k2b(const float* __restrict__ r1,
    const float* __restrict__ W1, const float* __restrict__ g1, const float* __restrict__ bt1,
    const float* __restrict__ W2, float4* __restrict__ T1)
{
    __shared__ float ssum[10], mean[5], varr[5];
    int t = threadIdx.x;
    if (t < 10) { float s=0.f; for (int j=0;j<64;j++) s += r1[j*10+t]; ssum[t]=s; }
    __syncthreads();
    if (t < 5) {
        float m = ssum[t] / (float)NTOT;
        mean[t] = m;
        varr[t] = ssum[5+t] / (float)NTOT - m*m;
    }
    __syncthreads();
    if (t < 160) {
        int b = t >> 5, f = t & 31;
        float w = W1[t];
        float c = w * rsqrtf(w*w*varr[b] + EPS) * g1[t];
        T1[b*33 + f] = make_float4(c, bt1[t] - c*mean[b], W2[t*2], W2[t*2+1]);
    }
}

// ---------------- K3: BN1-affine+relu+W2 (padded float4 table), GCN2 aggregate ----------------
__global__ __launch_bounds__(64) void k3_gcn2(
    const float* __restrict__ u, const int* __restrict__ srcs, const int* __restrict__ dsts,
    const float4* __restrict__ T1, const float* __restrict__ b2,
    float2* __restrict__ pre2)
{
    __shared__ float4 T1l[165];          // padded: band b at float4 offset 33*b → banks 4b..4b+3 per f
    __shared__ float  ug[95];            // as stored: [v*5+b]
    __shared__ float  degs[NNODE], dinvs[NNODE];
    __shared__ float2 h2l[95];           // [b*19+v]
    __shared__ float2 aggl[95];          // [b*19+v]
    __shared__ float  b2l[10];
    int g = blockIdx.x, t = threadIdx.x;

    for (int i=t;i<165;i+=64) T1l[i] = T1[i];
    if (t<10) b2l[t]=b2[t];
    if (t<NNODE) degs[t]=0.f;
    for (int i=t;i<190;i+=64) ((float*)aggl)[i]=0.f;
    for (int i=t;i<95;i+=64) ug[i]=u[g*95+i];
    __syncthreads();

    int ls=0, ld=0;
    bool ee = (t < ES);
    if (ee) {
        ls = srcs[g*ES+t] - g*NNODE; ld = dsts[g*ES+t] - g*NNODE;
        atomicAdd(&degs[ld], 1.f);
    }
    __syncthreads();
    if (t<NNODE) dinvs[t] = rsqrtf(degs[t]+1.f);
    __syncthreads();

    for (int j=t;j<95;j+=64) {
        int b=j/19, v=j%19;
        float uv = ug[v*5+b];
        float hx=0.f, hy=0.f;
        #pragma unroll
        for (int f=0;f<32;f++) {
            float4 c = T1l[b*33+f];      // ds_read_b128, conflict-free across bands
            float r = fmaxf(fmaf(c.x, uv, c.y), 0.f);
            hx = fmaf(r, c.z, hx);
            hy = fmaf(r, c.w, hy);
        }
        h2l[j] = make_float2(hx, hy);
    }
    __syncthreads();
    if (ee) {
        float nm = dinvs[ls]*dinvs[ld];
        #pragma unroll
        for (int b=0;b<NB;b++) {
            float2 hv = h2l[b*19+ls];
            atomicAdd(&((float*)aggl)[(b*19+ld)*2+0], nm*hv.x);
            atomicAdd(&((float*)aggl)[(b*19+ld)*2+1], nm*hv.y);
        }
    }
    __syncthreads();
    for (int j=t;j<95;j+=64) {
        int b=j/19, v=j%19;
        float dd = dinvs[v]*dinvs[v];
        float2 h = h2l[j], a = aggl[j];
        pre2[(size_t)g*95 + j] = make_float2(a.x + dd*h.x + b2l[2*b],
                                             a.y + dd*h.y + b2l[2*b+1]);
    }
}

// ---------------- KR2: per-(band,k) sum & sumsq over PRE2 ----------------
__global__ __launch_bounds__(256) void kr2(const float2* __restrict__ pre2, float* __restrict__ r2)
{
    int t = threadIdx.x;
    int g0 = blockIdx.x*512 + t;          // 64 blocks x 512 graphs
    float2 s[5], q[5];
    #pragma unroll
    for (int b=0;b<5;b++){ s[b]=make_float2(0,0); q[b]=make_float2(0,0); }
    #pragma unroll
    for (int gg=0; gg<2; gg++) {
        const float2* p = pre2 + (size_t)(g0 + gg*256)*95;
        #pragma unroll
        for (int b=0;b<5;b++) {
            #pragma unroll
            for (int r=0;r<19;r++) {
                float2 v = p[b*19+r];
                s[b].x += v.x;     s[b].y += v.y;
                q[b].x += v.x*v.x; q[b].y += v.y*v.y;
            }
        }
    }
    __shared__ float red[256][20];
    #pragma unroll
    for (int b=0;b<5;b++) {
        red[t][2*b]=s[b].x;    red[t][2*b+1]=s[b].y;
        red[t][10+2*b]=q[b].x; red[t][10+2*b+1]=q[b].y;
    }
    __syncthreads();
    for (int off=128; off>0; off>>=1) {
        if (t < off) {
            #pragma unroll
            for (int k=0;k<20;k++) red[t][k] += red[t+off][k];
        }
        __syncthreads();
    }
    if (t < 20) r2[blockIdx.x*20 + t] = red[0][t];
}

// ---------------- K4b: finalize BN2 stats -> affine A2,D2 ----------------
__global__ __launch_bounds__(64) void k4b(const float* __restrict__ r2,
    const float* __restrict__ g2, const float* __restrict__ bt2,
    float* __restrict__ A2, float* __restrict__ D2)
{
    __shared__ float ssum[20];
    int t = threadIdx.x;
    if (t < 20) { float s=0.f; for (int j=0;j<64;j++) s += r2[j*20+t]; ssum[t]=s; }
    __syncthreads();
    if (t < 10) {
        float m = ssum[t] / (float)NTOT;
        float v = ssum[10+t] / (float)NTOT - m*m;
        float a = g2[t] * rsqrtf(v + EPS);
        A2[t] = a;
        D2[t] = bt2[t] - a*m;
    }
}

// ---------------- K4x: xc = relu(A2*pre2 + D2) in place ----------------
__global__ __launch_bounds__(256) void k4x_xc(float* __restrict__ pre2,
    const float* __restrict__ A2, const float* __restrict__ D2)
{
    __shared__ float a2[10], d2[10];
    if (threadIdx.x < 10) { a2[threadIdx.x]=A2[threadIdx.x]; d2[threadIdx.x]=D2[threadIdx.x]; }
    __syncthreads();
    const int total = BGR*95;
    for (int i = blockIdx.x*256 + threadIdx.x; i < total; i += gridDim.x*256) {
        int pp = i % 95;
        int b = pp / 19;
        float2 v = ((float2*)pre2)[i];
        v.x = fmaxf(fmaf(a2[b*2+0], v.x, d2[b*2+0]), 0.f);
        v.y = fmaxf(fmaf(a2[b*2+1], v.y, d2[b*2+1]), 0.f);
        ((float2*)pre2)[i] = v;
    }
}

// ---------------- K5: pre3 = xc @ lin1_W + b (thread=feature, 16 graphs/block) ----------------
__global__ __launch_bounds__(128) void k5_lin1(
    const float* __restrict__ xc, const float* __restrict__ W, const float* __restrict__ bias,
    float* __restrict__ pre3, float* __restrict__ p3)
{
    int bid = blockIdx.x, f = threadIdx.x;
    const float* xcb = xc + bid*16*190;   // wave-uniform base
    float acc[16];
    #pragma unroll
    for (int r=0;r<16;r++) acc[r]=0.f;
    for (int k=0;k<190;k++) {
        float w = W[k*128+f];
        #pragma unroll
        for (int r=0;r<16;r++) acc[r] = fmaf(xcb[r*190+k], w, acc[r]);  // uniform loads
    }
    float bb = bias[f];
    float s=0.f, s2=0.f;
    #pragma unroll
    for (int r=0;r<16;r++) {
        float p = acc[r]+bb;
        pre3[(bid*16+r)*128+f] = p;
        s += p; s2 += p*p;
    }
    p3[bid*256+f]     = s;
    p3[bid*256+128+f] = s2;
}

// ---------------- K6a/K6b: BN3 stats reduction -> affine A3,D3 ----------------
__global__ __launch_bounds__(256) void k6a(const float* __restrict__ p3, float* __restrict__ r3)
{
    int j = blockIdx.x, f = threadIdx.x;
    float s = 0.f;
    for (int r = j*32; r < (j+1)*32; r++) s += p3[r*256+f];
    r3[j*256+f] = s;
}

__global__ __launch_bounds__(128) void k6b(const float* __restrict__ r3,
    const float* __restrict__ g3, const float* __restrict__ bt3,
    float* __restrict__ A3, float* __restrict__ D3)
{
    int f = threadIdx.x;
    float s=0.f, q=0.f;
    for (int j=0;j<64;j++) { s += r3[j*256+f]; q += r3[j*256+128+f]; }
    float m = s / (float)BGR;
    float v = q / (float)BGR - m*m;
    float a = g3[f] * rsqrtf(v + EPS);
    A3[f] = a;
    D3[f] = bt3[f] - a*m;
}

// ---------------- K7: head, thread per graph ----------------
__global__ __launch_bounds__(256) void k7_head(
    const float* __restrict__ pre3, const float* __restrict__ A3, const float* __restrict__ D3,
    const float* __restrict__ W2h, const float* __restrict__ b2h,
    const float* __restrict__ W3h, const float* __restrict__ b3h,
    float* __restrict__ out)
{
    int g = blockIdx.x*256 + threadIdx.x;
    float accj[32];
    #pragma unroll
    for (int j=0;j<32;j++) accj[j] = b2h[j];
    const float* p3 = pre3 + g*128;
    #pragma unroll 2
    for (int f4=0; f4<128; f4+=4) {
        float4 pv = *(const float4*)(p3 + f4);
        float y0 = fmaxf(fmaf(A3[f4+0], pv.x, D3[f4+0]), 0.f);
        float y1 = fmaxf(fmaf(A3[f4+1], pv.y, D3[f4+1]), 0.f);
        float y2 = fmaxf(fmaf(A3[f4+2], pv.z, D3[f4+2]), 0.f);
        float y3 = fmaxf(fmaf(A3[f4+3], pv.w, D3[f4+3]), 0.f);
        #pragma unroll
        for (int j=0;j<32;j++) {
            accj[j] = fmaf(y0, W2h[(f4+0)*32+j], accj[j]);
            accj[j] = fmaf(y1, W2h[(f4+1)*32+j], accj[j]);
            accj[j] = fmaf(y2, W2h[(f4+2)*32+j], accj[j]);
            accj[j] = fmaf(y3, W2h[(f4+3)*32+j], accj[j]);
        }
    }
    float o0 = b3h[0], o1 = b3h[1];
    #pragma unroll
    for (int j=0;j<32;j++) {
        float yj = fmaxf(accj[j], 0.f);
        o0 = fmaf(yj, W3h[j*2+0], o0);
        o1 = fmaf(yj, W3h[j*2+1], o1);
    }
    ((float2*)out)[g] = make_float2(o0, o1);
}

extern "C" void kernel_launch(void* const* d_in, const int* in_sizes, int n_in,
                              void* d_out, int out_size, void* d_ws, size_t ws_size,
                              hipStream_t stream)
{
    (void)in_sizes; (void)n_in; (void)out_size; (void)ws_size;
    const float* x    = (const float*)d_in[0];
    const float* ew   = (const float*)d_in[1];
    const int*   eif  = (const int*)d_in[2];
    const int*   eis  = (const int*)d_in[3];
    const float* W1   = (const float*)d_in[4];
    // d_in[5] = b1: cancels exactly inside BN1 (mean subtraction) — unused
    const float* g1   = (const float*)d_in[6];
    const float* bt1  = (const float*)d_in[7];
    const float* W2   = (const float*)d_in[8];
    const float* b2   = (const float*)d_in[9];
    const float* g2   = (const float*)d_in[10];
    const float* bt2  = (const float*)d_in[11];
    const float* l1W  = (const float*)d_in[12];
    const float* l1b  = (const float*)d_in[13];
    const float* g3   = (const float*)d_in[14];
    const float* bt3  = (const float*)d_in[15];
    const float* l2W  = (const float*)d_in[16];
    const float* l2b  = (const float*)d_in[17];
    const float* l3W  = (const float*)d_in[18];
    const float* l3b  = (const float*)d_in[19];
    float* out = (float*)d_out;
    float* ws  = (float*)d_ws;

    const int* srcf = eif;  const int* dstf = eif + BGR*EF;
    const int* srcs = eis;  const int* dsts = eis + BGR*ES;

    float* U    = ws + WS_U;
    float* PRE2 = ws + WS_PRE2;
    float* PRE3 = ws + WS_PRE3;
    float* R1   = ws + WS_R1;
    float* R2   = ws + WS_R2;
    float* P3   = ws + WS_P3;
    float* R3   = ws + WS_R3;
    float4* T1  = (float4*)(ws + WS_T1);
    float* A2   = ws + WS_A2;
    float* D2   = ws + WS_D2;
    float* A3   = ws + WS_A3;
    float* D3   = ws + WS_D3;

    k1_gcn1<<<BGR, 64, 0, stream>>>(x, ew, srcf, dstf, U);
    kr1<<<64, 256, 0, stream>>>(U, R1);
    k2b<<<1, 256, 0, stream>>>(R1, W1, g1, bt1, W2, T1);
    k3_gcn2<<<BGR, 64, 0, stream>>>(U, srcs, dsts, T1, b2, (float2*)PRE2);
    kr2<<<64, 256, 0, stream>>>((const float2*)PRE2, R2);
    k4b<<<1, 64, 0, stream>>>(R2, g2, bt2, A2, D2);
    k4x_xc<<<2048, 256, 0, stream>>>(PRE2, A2, D2);
    k5_lin1<<<2048, 128, 0, stream>>>(PRE2, l1W, l1b, PRE3, P3);
    k6a<<<64, 256, 0, stream>>>(P3, R3);
    k6b<<<1, 128, 0, stream>>>(R3, g3, bt3, A3, D3);
    k7_head<<<BGR/256, 256, 0, stream>>>(PRE3, A3, D3, l2W, l2b, l3W, l3b, out);
}

// Round 3
// 567.764 us; speedup vs baseline: 1.1550x; 1.0146x over previous
//
#include <hip/hip_runtime.h>
#include <hip/hip_fp16.h>

#define BGR 32768
#define NNODE 19
#define NTOT (BGR*NNODE)       // 622592
#define EF 120
#define ES 60
#define NB 5
#define EPS 1e-5f

// ---- workspace layout (float offsets) ----
#define WS_U     0                          // NTOT*NB  = 3,112,960
#define WS_PRE2  (WS_U + NTOT*NB)           // BGR*190  = 6,225,920 (xc in-place)
#define WS_PRE3  (WS_PRE2 + BGR*190)        // BGR*128  = 4,194,304
#define WS_H2    (WS_PRE3 + BGR*128)        // NTOT*NB uints (half2 packed)
#define WS_P3    (WS_H2 + NTOT*NB)          // 2048*256
#define WS_R3    (WS_P3 + 2048*256)         // 64*256
#define WS_R1    (WS_R3 + 64*256)           // 640
#define WS_R2    (WS_R1 + 640)              // 1280
#define WS_T1    (WS_R2 + 1280)             // 5*33*4 = 660 (16B-aligned offset)
#define WS_A2    (WS_T1 + 660)              // 10
#define WS_D2    (WS_A2 + 16)               // 10
#define WS_A3    (WS_D2 + 16)               // 128
#define WS_D3    (WS_A3 + 128)              // 128

// ---------------- K1: GCN1 -> scalar u per (node,band). wave-per-graph, 4 graphs/block ----------------
__global__ __launch_bounds__(256) void k1_gcn1(
    const float* __restrict__ x, const float* __restrict__ ew,
    const int* __restrict__ srcf, const int* __restrict__ dstf,
    float* __restrict__ u)
{
    __shared__ float xg[4][95];
    __shared__ float z2[4][2][95];     // 2-copy split: halves same-address atomic serialization
    __shared__ float deg2[4][2][19];
    __shared__ float dinv[4][19];
    int t = threadIdx.x, q = t >> 6, lane = t & 63;
    int g = blockIdx.x*4 + q;

    for (int i = lane; i < 95; i += 64) xg[q][i] = x[g*95 + i];
    for (int i = lane; i < 190; i += 64) ((float*)z2[q])[i] = 0.f;
    if (lane < 38) ((float*)deg2[q])[lane] = 0.f;

    int s0, d0, s1=0, d1=0; float w0, w1=0.f;
    bool e1 = (lane + 64 < EF);
    s0 = srcf[g*EF+lane] - g*NNODE; d0 = dstf[g*EF+lane] - g*NNODE; w0 = ew[g*EF+lane];
    if (e1) { s1 = srcf[g*EF+lane+64] - g*NNODE; d1 = dstf[g*EF+lane+64] - g*NNODE; w1 = ew[g*EF+lane+64]; }
    __syncthreads();
    int c = lane & 1;
    atomicAdd(&deg2[q][c][d0], w0);
    if (e1) atomicAdd(&deg2[q][c][d1], w1);
    __syncthreads();
    if (lane < NNODE) dinv[q][lane] = rsqrtf(deg2[q][0][lane] + deg2[q][1][lane] + 1.f);
    __syncthreads();
    {
        float nm = dinv[q][s0]*w0*dinv[q][d0];
        #pragma unroll
        for (int b=0;b<NB;b++) atomicAdd(&z2[q][c][d0*5+b], nm*xg[q][s0*5+b]);
    }
    if (e1) {
        float nm = dinv[q][s1]*w1*dinv[q][d1];
        #pragma unroll
        for (int b=0;b<NB;b++) atomicAdd(&z2[q][c][d1*5+b], nm*xg[q][s1*5+b]);
    }
    __syncthreads();
    for (int i = lane; i < 95; i += 64) {
        float di = dinv[q][i/5];
        u[g*95 + i] = z2[q][0][i] + z2[q][1][i] + di*di*xg[q][i];
    }
}

// ---------------- KR1: per-band sum & sumsq over U ----------------
__global__ __launch_bounds__(256) void kr1(const float* __restrict__ U, float* __restrict__ r1)
{
    int j = blockIdx.x;                    // 64 blocks
    const int CH = NTOT*NB/64;             // 48640, divisible by 5
    const float* base = U + j*CH;
    float s[5], q[5];
    #pragma unroll
    for (int b=0;b<5;b++){ s[b]=0.f; q[b]=0.f; }
    #pragma unroll
    for (int b=0;b<5;b++) {
        for (int m = threadIdx.x; m < CH/5; m += 256) {
            float v = base[5*m + b];       // global idx %5 == b  (band)
            s[b]+=v; q[b]+=v*v;
        }
    }
    __shared__ float red[256][10];
    #pragma unroll
    for (int b=0;b<5;b++){ red[threadIdx.x][b]=s[b]; red[threadIdx.x][5+b]=q[b]; }
    __syncthreads();
    for (int off=128; off>0; off>>=1) {
        if ((int)threadIdx.x < off) {
            #pragma unroll
            for (int k=0;k<10;k++) red[threadIdx.x][k] += red[threadIdx.x+off][k];
        }
        __syncthreads();
    }
    if (threadIdx.x < 10) r1[j*10 + threadIdx.x] = red[0][threadIdx.x];
}

// ---------------- K2b: BN1 stats -> packed padded table T1[b][33] = (A1,D1,W2_0,W2_1) ----------------
__global__ __launch_bounds__(256) void k2b(const float* __restrict__ r1,
    const float* __restrict__ W1, const float* __restrict__ g1, const float* __restrict__ bt1,
    const float* __restrict__ W2, float4* __restrict__ T1)
{
    __shared__ float ssum[10], mean[5], varr[5];
    int t = threadIdx.x;
    if (t < 10) { float s=0.f; for (int j=0;j<64;j++) s += r1[j*10+t]; ssum[t]=s; }
    __syncthreads();
    if (t < 5) {
        float m = ssum[t] / (float)NTOT;
        mean[t] = m;
        varr[t] = ssum[5+t] / (float)NTOT - m*m;
    }
    __syncthreads();
    if (t < 160) {
        int b = t >> 5, f = t & 31;
        float w = W1[t];
        float c = w * rsqrtf(w*w*varr[b] + EPS) * g1[t];
        T1[b*33 + f] = make_float4(c, bt1[t] - c*mean[b], W2[t*2], W2[t*2+1]);
    }
}

// ---------------- K3a: dense h2 = W2*relu(A1*u+D1), band-uniform blocks -> scalar-pipe table loads ----------------
__global__ __launch_bounds__(256) void k3a(
    const float* __restrict__ u, const float4* __restrict__ T1p,
    unsigned int* __restrict__ H2)
{
    int b = blockIdx.x % 5;                          // block-uniform -> s_load for table
    int node = (blockIdx.x/5)*256 + (int)threadIdx.x;
    float uv = u[node*5 + b];
    const float4* Tb = T1p + b*33;
    float hx = 0.f, hy = 0.f;
    #pragma unroll
    for (int f=0; f<32; f++) {
        float4 cc = Tb[f];                           // wave-uniform -> scalar loads
        float r = fmaxf(fmaf(cc.x, uv, cc.y), 0.f);
        hx = fmaf(r, cc.z, hx);
        hy = fmaf(r, cc.w, hy);
    }
    __half2 h = __floats2half2_rn(hx, hy);
    H2[(size_t)b*NTOT + node] = *(unsigned int*)&h;
}

// ---------------- K3b: GCN2 aggregate only. wave-per-graph, 4 graphs/block ----------------
__global__ __launch_bounds__(256) void k3b(
    const unsigned int* __restrict__ H2, const int* __restrict__ srcs, const int* __restrict__ dsts,
    const float* __restrict__ b2, float2* __restrict__ pre2)
{
    __shared__ unsigned int h2l[4][95];
    __shared__ float agg2[4][2][190];  // 2-copy split
    __shared__ float degs[4][NNODE];
    __shared__ float dinvs[4][NNODE];
    __shared__ float b2l[10];
    int t = threadIdx.x, q = t>>6, lane = t&63;
    int g = blockIdx.x*4 + q;

    if (t < 10) b2l[t] = b2[t];
    for (int i=lane;i<95;i+=64) {
        int b = i/19, v = i - b*19;
        h2l[q][i] = H2[(size_t)b*NTOT + g*19 + v];
    }
    for (int i=lane;i<380;i+=64) ((float*)agg2[q])[i] = 0.f;
    if (lane < NNODE) degs[q][lane] = 0.f;
    int ls=0, ld=0; bool ee = lane < ES;
    if (ee) { ls = srcs[g*ES+lane]-g*NNODE; ld = dsts[g*ES+lane]-g*NNODE; }
    __syncthreads();
    if (ee) atomicAdd(&degs[q][ld], 1.f);
    __syncthreads();
    if (lane < NNODE) dinvs[q][lane] = rsqrtf(degs[q][lane] + 1.f);
    __syncthreads();
    if (ee) {
        float nm = dinvs[q][ls]*dinvs[q][ld];
        int c = lane & 1;
        #pragma unroll
        for (int b=0;b<NB;b++) {
            unsigned int hv = h2l[q][b*19+ls];
            float2 h = __half22float2(*(__half2*)&hv);
            atomicAdd(&agg2[q][c][(b*19+ld)*2+0], nm*h.x);
            atomicAdd(&agg2[q][c][(b*19+ld)*2+1], nm*h.y);
        }
    }
    __syncthreads();
    for (int i=lane;i<95;i+=64) {
        int b = i/19;
        float dd = dinvs[q][i - b*19]; dd *= dd;
        unsigned int hv = h2l[q][i];
        float2 h = __half22float2(*(__half2*)&hv);
        pre2[(size_t)g*95 + i] = make_float2(
            agg2[q][0][2*i]   + agg2[q][1][2*i]   + dd*h.x + b2l[2*b],
            agg2[q][0][2*i+1] + agg2[q][1][2*i+1] + dd*h.y + b2l[2*b+1]);
    }
}

// ---------------- KR2: per-(band,k) sum & sumsq over PRE2 ----------------
__global__ __launch_bounds__(256) void kr2(const float2* __restrict__ pre2, float* __restrict__ r2)
{
    int t = threadIdx.x;
    int g0 = blockIdx.x*512 + t;          // 64 blocks x 512 graphs
    float2 s[5], q[5];
    #pragma unroll
    for (int b=0;b<5;b++){ s[b]=make_float2(0,0); q[b]=make_float2(0,0); }
    #pragma unroll
    for (int gg=0; gg<2; gg++) {
        const float2* p = pre2 + (size_t)(g0 + gg*256)*95;
        #pragma unroll
        for (int b=0;b<5;b++) {
            #pragma unroll
            for (int r=0;r<19;r++) {
                float2 v = p[b*19+r];
                s[b].x += v.x;     s[b].y += v.y;
                q[b].x += v.x*v.x; q[b].y += v.y*v.y;
            }
        }
    }
    __shared__ float red[256][20];
    #pragma unroll
    for (int b=0;b<5;b++) {
        red[t][2*b]=s[b].x;    red[t][2*b+1]=s[b].y;
        red[t][10+2*b]=q[b].x; red[t][10+2*b+1]=q[b].y;
    }
    __syncthreads();
    for (int off=128; off>0; off>>=1) {
        if (t < off) {
            #pragma unroll
            for (int k=0;k<20;k++) red[t][k] += red[t+off][k];
        }
        __syncthreads();
    }
    if (t < 20) r2[blockIdx.x*20 + t] = red[0][t];
}

// ---------------- K4b: finalize BN2 stats -> affine A2,D2 ----------------
__global__ __launch_bounds__(64) void k4b(const float* __restrict__ r2,
    const float* __restrict__ g2, const float* __restrict__ bt2,
    float* __restrict__ A2, float* __restrict__ D2)
{
    __shared__ float ssum[20];
    int t = threadIdx.x;
    if (t < 20) { float s=0.f; for (int j=0;j<64;j++) s += r2[j*20+t]; ssum[t]=s; }
    __syncthreads();
    if (t < 10) {
        float m = ssum[t] / (float)NTOT;
        float v = ssum[10+t] / (float)NTOT - m*m;
        float a = g2[t] * rsqrtf(v + EPS);
        A2[t] = a;
        D2[t] = bt2[t] - a*m;
    }
}

// ---------------- K4x: xc = relu(A2*pre2 + D2) in place ----------------
__global__ __launch_bounds__(256) void k4x_xc(float* __restrict__ pre2,
    const float* __restrict__ A2, const float* __restrict__ D2)
{
    __shared__ float a2[10], d2[10];
    if (threadIdx.x < 10) { a2[threadIdx.x]=A2[threadIdx.x]; d2[threadIdx.x]=D2[threadIdx.x]; }
    __syncthreads();
    const int total = BGR*95;
    for (int i = blockIdx.x*256 + threadIdx.x; i < total; i += gridDim.x*256) {
        int pp = i % 95;
        int b = pp / 19;
        float2 v = ((float2*)pre2)[i];
        v.x = fmaxf(fmaf(a2[b*2+0], v.x, d2[b*2+0]), 0.f);
        v.y = fmaxf(fmaf(a2[b*2+1], v.y, d2[b*2+1]), 0.f);
        ((float2*)pre2)[i] = v;
    }
}

// ---------------- K5: pre3 = xc @ lin1_W + b (thread=feature, 16 graphs/block) ----------------
__global__ __launch_bounds__(128) void k5_lin1(
    const float* __restrict__ xc, const float* __restrict__ W, const float* __restrict__ bias,
    float* __restrict__ pre3, float* __restrict__ p3)
{
    int bid = blockIdx.x, f = threadIdx.x;
    const float* xcb = xc + bid*16*190;   // wave-uniform base
    float acc[16];
    #pragma unroll
    for (int r=0;r<16;r++) acc[r]=0.f;
    for (int k=0;k<190;k++) {
        float w = W[k*128+f];
        #pragma unroll
        for (int r=0;r<16;r++) acc[r] = fmaf(xcb[r*190+k], w, acc[r]);  // uniform loads
    }
    float bb = bias[f];
    float s=0.f, s2=0.f;
    #pragma unroll
    for (int r=0;r<16;r++) {
        float p = acc[r]+bb;
        pre3[(bid*16+r)*128+f] = p;
        s += p; s2 += p*p;
    }
    p3[bid*256+f]     = s;
    p3[bid*256+128+f] = s2;
}

// ---------------- K6a/K6b: BN3 stats reduction -> affine A3,D3 ----------------
__global__ __launch_bounds__(256) void k6a(const float* __restrict__ p3, float* __restrict__ r3)
{
    int j = blockIdx.x, f = threadIdx.x;
    float s = 0.f;
    for (int r = j*32; r < (j+1)*32; r++) s += p3[r*256+f];
    r3[j*256+f] = s;
}

__global__ __launch_bounds__(128) void k6b(const float* __restrict__ r3,
    const float* __restrict__ g3, const float* __restrict__ bt3,
    float* __restrict__ A3, float* __restrict__ D3)
{
    int f = threadIdx.x;
    float s=0.f, q=0.f;
    for (int j=0;j<64;j++) { s += r3[j*256+f]; q += r3[j*256+128+f]; }
    float m = s / (float)BGR;
    float v = q / (float)BGR - m*m;
    float a = g3[f] * rsqrtf(v + EPS);
    A3[f] = a;
    D3[f] = bt3[f] - a*m;
}

// ---------------- K7: head, thread per graph ----------------
__global__ __launch_bounds__(256) void k7_head(
    const float* __restrict__ pre3, const float* __restrict__ A3, const float* __restrict__ D3,
    const float* __restrict__ W2h, const float* __restrict__ b2h,
    const float* __restrict__ W3h, const float* __restrict__ b3h,
    float* __restrict__ out)
{
    int g = blockIdx.x*256 + threadIdx.x;
    float accj[32];
    #pragma unroll
    for (int j=0;j<32;j++) accj[j] = b2h[j];
    const float* p3 = pre3 + g*128;
    #pragma unroll 2
    for (int f4=0; f4<128; f4+=4) {
        float4 pv = *(const float4*)(p3 + f4);
        float y0 = fmaxf(fmaf(A3[f4+0], pv.x, D3[f4+0]), 0.f);
        float y1 = fmaxf(fmaf(A3[f4+1], pv.y, D3[f4+1]), 0.f);
        float y2 = fmaxf(fmaf(A3[f4+2], pv.z, D3[f4+2]), 0.f);
        float y3 = fmaxf(fmaf(A3[f4+3], pv.w, D3[f4+3]), 0.f);
        #pragma unroll
        for (int j=0;j<32;j++) {
            accj[j] = fmaf(y0, W2h[(f4+0)*32+j], accj[j]);
            accj[j] = fmaf(y1, W2h[(f4+1)*32+j], accj[j]);
            accj[j] = fmaf(y2, W2h[(f4+2)*32+j], accj[j]);
            accj[j] = fmaf(y3, W2h[(f4+3)*32+j], accj[j]);
        }
    }
    float o0 = b3h[0], o1 = b3h[1];
    #pragma unroll
    for (int j=0;j<32;j++) {
        float yj = fmaxf(accj[j], 0.f);
        o0 = fmaf(yj, W3h[j*2+0], o0);
        o1 = fmaf(yj, W3h[j*2+1], o1);
    }
    ((float2*)out)[g] = make_float2(o0, o1);
}

extern "C" void kernel_launch(void* const* d_in, const int* in_sizes, int n_in,
                              void* d_out, int out_size, void* d_ws, size_t ws_size,
                              hipStream_t stream)
{
    (void)in_sizes; (void)n_in; (void)out_size; (void)ws_size;
    const float* x    = (const float*)d_in[0];
    const float* ew   = (const float*)d_in[1];
    const int*   eif  = (const int*)d_in[2];
    const int*   eis  = (const int*)d_in[3];
    const float* W1   = (const float*)d_in[4];
    // d_in[5] = b1: cancels exactly inside BN1 (mean subtraction) — unused
    const float* g1   = (const float*)d_in[6];
    const float* bt1  = (const float*)d_in[7];
    const float* W2   = (const float*)d_in[8];
    const float* b2   = (const float*)d_in[9];
    const float* g2   = (const float*)d_in[10];
    const float* bt2  = (const float*)d_in[11];
    const float* l1W  = (const float*)d_in[12];
    const float* l1b  = (const float*)d_in[13];
    const float* g3   = (const float*)d_in[14];
    const float* bt3  = (const float*)d_in[15];
    const float* l2W  = (const float*)d_in[16];
    const float* l2b  = (const float*)d_in[17];
    const float* l3W  = (const float*)d_in[18];
    const float* l3b  = (const float*)d_in[19];
    float* out = (float*)d_out;
    float* ws  = (float*)d_ws;

    const int* srcf = eif;  const int* dstf = eif + BGR*EF;
    const int* srcs = eis;  const int* dsts = eis + BGR*ES;

    float* U    = ws + WS_U;
    float* PRE2 = ws + WS_PRE2;
    float* PRE3 = ws + WS_PRE3;
    unsigned int* H2 = (unsigned int*)(ws + WS_H2);
    float* P3   = ws + WS_P3;
    float* R3   = ws + WS_R3;
    float* R1   = ws + WS_R1;
    float* R2   = ws + WS_R2;
    float4* T1  = (float4*)(ws + WS_T1);
    float* A2   = ws + WS_A2;
    float* D2   = ws + WS_D2;
    float* A3   = ws + WS_A3;
    float* D3   = ws + WS_D3;

    k1_gcn1<<<BGR/4, 256, 0, stream>>>(x, ew, srcf, dstf, U);
    kr1<<<64, 256, 0, stream>>>(U, R1);
    k2b<<<1, 256, 0, stream>>>(R1, W1, g1, bt1, W2, T1);
    k3a<<<(NTOT/256)*5, 256, 0, stream>>>(U, T1, H2);
    k3b<<<BGR/4, 256, 0, stream>>>(H2, srcs, dsts, b2, (float2*)PRE2);
    kr2<<<64, 256, 0, stream>>>((const float2*)PRE2, R2);
    k4b<<<1, 64, 0, stream>>>(R2, g2, bt2, A2, D2);
    k4x_xc<<<2048, 256, 0, stream>>>(PRE2, A2, D2);
    k5_lin1<<<2048, 128, 0, stream>>>(PRE2, l1W, l1b, PRE3, P3);
    k6a<<<64, 256, 0, stream>>>(P3, R3);
    k6b<<<1, 128, 0, stream>>>(R3, g3, bt3, A3, D3);
    k7_head<<<BGR/256, 256, 0, stream>>>(PRE3, A3, D3, l2W, l2b, l3W, l3b, out);
}

// Round 4
// 372.412 us; speedup vs baseline: 1.7609x; 1.5246x over previous
//
#include <hip/hip_runtime.h>
#include <hip/hip_fp16.h>

#define BGR 32768
#define NNODE 19
#define NTOT (BGR*NNODE)       // 622592
#define EF 120
#define ES 60
#define NB 5
#define EPS 1e-5f

// ---- workspace layout (float offsets) ----
#define WS_U     0                          // NTOT*NB (band-major [b][node])
#define WS_PRE2  (WS_U + NTOT*NB)           // BGR*190 (node-major [g][v*10+b*2+kk], xc in place)
#define WS_PRE3  (WS_PRE2 + BGR*190)        // BGR*128
#define WS_H2    (WS_PRE3 + BGR*128)        // NTOT*NB uints (half2, band-major)
#define WS_P3    (WS_H2 + NTOT*NB)          // 2048*256
#define WS_R3    (WS_P3 + 2048*256)         // 64*256
#define WS_R1    (WS_R3 + 64*256)           // 160*2
#define WS_R2    (WS_R1 + 320)              // 320*20
#define WS_T1    (WS_R2 + 6400)             // 165 float4 (offset %4 == 0)
#define WS_A2    (WS_T1 + 660)              // 10
#define WS_D2    (WS_A2 + 16)               // 10
#define WS_A3    (WS_D2 + 16)               // 128
#define WS_D3    (WS_A3 + 128)              // 128

// ---------------- K1: dense-N GCN1 -> u (band-major). wave/graph, 4 graphs/block ----------------
__global__ __launch_bounds__(256) void k1_gcn1(
    const float* __restrict__ x, const float* __restrict__ ew,
    const int* __restrict__ srcf, const int* __restrict__ dstf,
    float* __restrict__ Ub)
{
    __shared__ float xg[4][96];        // x, then scaled by dinv[s] in place
    __shared__ float Nr[4][380];       // raw weighted adjacency [d][s], row pitch 20
    __shared__ float dinv[4][20];
    int t = threadIdx.x, q = t >> 6, lane = t & 63;
    int g = blockIdx.x*4 + q;

    // early global loads (latency overlapped with LDS init)
    int s0, d0, s1 = 0, d1 = 0; float w0, w1 = 0.f;
    bool e1 = (lane < EF - 64);
    s0 = srcf[g*EF+lane] - g*NNODE; d0 = dstf[g*EF+lane] - g*NNODE; w0 = ew[g*EF+lane];
    if (e1) { s1 = srcf[g*EF+lane+64] - g*NNODE; d1 = dstf[g*EF+lane+64] - g*NNODE; w1 = ew[g*EF+lane+64]; }
    for (int i = lane; i < 95; i += 64) xg[q][i] = x[g*95 + i];
    for (int i = lane; i < 380; i += 64) Nr[q][i] = 0.f;
    __syncthreads();

    atomicAdd(&Nr[q][d0*20 + s0], w0);       // one atomic per edge (random slots)
    if (e1) atomicAdd(&Nr[q][d1*20 + s1], w1);
    __syncthreads();

    if (lane < NNODE) {
        float s = 0.f;
        #pragma unroll
        for (int k = 0; k < 19; k++) s += Nr[q][lane*20 + k];
        dinv[q][lane] = rsqrtf(s + 1.f);
    }
    __syncthreads();
    for (int i = lane; i < 95; i += 64) xg[q][i] *= dinv[q][i/5];   // xg := dinv[s]*x[s][b]
    __syncthreads();

    for (int i = lane; i < 95; i += 64) {
        int b = i/19, v = i - 19*b;          // band-major output grouping
        float acc = xg[q][v*5 + b];          // self: dinv[v]^2*x = dv*(dinv[v]*x)
        #pragma unroll
        for (int s = 0; s < 19; s++) acc += Nr[q][v*20 + s] * xg[q][s*5 + b];
        Ub[(size_t)b*NTOT + g*19 + v] = dinv[q][v] * acc;
    }
}

// ---------------- KR1: (sum,sumsq) over band-major U, 160 coalesced blocks ----------------
__global__ __launch_bounds__(256) void kr1(const float* __restrict__ U, float* __restrict__ r1)
{
    const float4* base = (const float4*)(U + (size_t)blockIdx.x * (NTOT/32));   // 19456 floats
    float s = 0.f, qq = 0.f;
    for (int n = (int)threadIdx.x; n < NTOT/128; n += 256) {
        float4 v = base[n];
        s += v.x + v.y + v.z + v.w;
        qq += v.x*v.x + v.y*v.y + v.z*v.z + v.w*v.w;
    }
    __shared__ float red[256][2];
    red[threadIdx.x][0] = s; red[threadIdx.x][1] = qq;
    __syncthreads();
    for (int off = 128; off > 0; off >>= 1) {
        if ((int)threadIdx.x < off) {
            red[threadIdx.x][0] += red[threadIdx.x+off][0];
            red[threadIdx.x][1] += red[threadIdx.x+off][1];
        }
        __syncthreads();
    }
    if (threadIdx.x < 2) r1[blockIdx.x*2 + threadIdx.x] = red[0][threadIdx.x];
}

// ---------------- K2b: BN1 stats -> packed padded table T1[b][33] = (A1,D1,W2_0,W2_1) ----------------
__global__ __launch_bounds__(256) void k2b(const float* __restrict__ r1,
    const float* __restrict__ W1, const float* __restrict__ g1, const float* __restrict__ bt1,
    const float* __restrict__ W2, float4* __restrict__ T1)
{
    __shared__ float mean[5], varr[5];
    int t = threadIdx.x;
    if (t < 5) {
        float s = 0.f, qq = 0.f;
        for (int j = 0; j < 32; j++) { s += r1[(t*32+j)*2]; qq += r1[(t*32+j)*2+1]; }
        float m = s / (float)NTOT;
        mean[t] = m;
        varr[t] = qq / (float)NTOT - m*m;
    }
    __syncthreads();
    if (t < 160) {
        int b = t >> 5;
        float w = W1[t];
        float c = w * rsqrtf(w*w*varr[b] + EPS) * g1[t];
        T1[b*33 + (t & 31)] = make_float4(c, bt1[t] - c*mean[b], W2[t*2], W2[t*2+1]);
    }
}

// ---------------- K3a: dense h2 map, band-uniform block, fully coalesced ----------------
__global__ __launch_bounds__(256) void k3a(
    const float* __restrict__ Ub, const float4* __restrict__ T1p,
    unsigned int* __restrict__ H2)
{
    int bb = blockIdx.x / (NTOT/256);                 // block-uniform band -> s_loads
    int node = (blockIdx.x - bb*(NTOT/256))*256 + (int)threadIdx.x;
    float uv = Ub[(size_t)bb*NTOT + node];            // coalesced
    const float4* Tb = T1p + bb*33;
    float hx = 0.f, hy = 0.f;
    #pragma unroll
    for (int f = 0; f < 32; f++) {
        float4 c = Tb[f];                             // wave-uniform scalar loads
        float r = fmaxf(fmaf(c.x, uv, c.y), 0.f);
        hx = fmaf(r, c.z, hx);
        hy = fmaf(r, c.w, hy);
    }
    __half2 h = __floats2half2_rn(hx, hy);
    H2[(size_t)bb*NTOT + node] = *(unsigned int*)&h;  // coalesced
}

// ---------------- K3b: dense-M GCN2 aggregate. wave/graph, 4 graphs/block ----------------
__global__ __launch_bounds__(256) void k3b(
    const unsigned int* __restrict__ H2, const int* __restrict__ srcs, const int* __restrict__ dsts,
    const float* __restrict__ b2, float2* __restrict__ pre2)
{
    __shared__ float2 h2l[4][96];      // [s*5+b], pre-scaled by dinv[s]
    __shared__ float  Mr[4][380];      // struct adjacency counts [d][s], pitch 20
    __shared__ float  dinv[4][20];
    __shared__ float  b2l[12];
    int t = threadIdx.x, q = t >> 6, lane = t & 63;
    int g = blockIdx.x*4 + q;

    // early global loads
    int b0 = lane/19, v0 = lane - 19*b0;
    unsigned int h0 = H2[(size_t)b0*NTOT + g*19 + v0];
    int b1 = (lane+64)/19, v1 = (lane+64) - 19*b1;
    unsigned int h1 = (lane < 31) ? H2[(size_t)b1*NTOT + g*19 + v1] : 0u;
    int ls = 0, ld = 0; bool ee = (lane < ES);
    if (ee) { ls = srcs[g*ES+lane] - g*NNODE; ld = dsts[g*ES+lane] - g*NNODE; }
    if (t < 10) b2l[t] = b2[t];
    for (int i = lane; i < 380; i += 64) Mr[q][i] = 0.f;
    __syncthreads();

    if (ee) atomicAdd(&Mr[q][ld*20 + ls], 1.f);
    __syncthreads();

    if (lane < NNODE) {
        float s = 0.f;
        #pragma unroll
        for (int k = 0; k < 19; k++) s += Mr[q][lane*20 + k];
        dinv[q][lane] = rsqrtf(s + 1.f);
    }
    __syncthreads();

    { // store h2 scaled by dinv[s]
        float2 f0 = __half22float2(*(__half2*)&h0);
        float sc = dinv[q][v0];
        h2l[q][v0*5 + b0] = make_float2(f0.x*sc, f0.y*sc);
        if (lane < 31) {
            float2 f1 = __half22float2(*(__half2*)&h1);
            float sc1 = dinv[q][v1];
            h2l[q][v1*5 + b1] = make_float2(f1.x*sc1, f1.y*sc1);
        }
    }
    __syncthreads();

    for (int i = lane; i < 95; i += 64) {
        int v = i/5, b = i - 5*v;
        float2 acc = h2l[q][i];                       // self term
        #pragma unroll
        for (int s = 0; s < 19; s++) {
            float m = Mr[q][v*20 + s];
            float2 hh = h2l[q][s*5 + b];
            acc.x = fmaf(m, hh.x, acc.x);
            acc.y = fmaf(m, hh.y, acc.y);
        }
        float dv = dinv[q][v];
        pre2[(size_t)g*95 + i] = make_float2(fmaf(dv, acc.x, b2l[2*b]),
                                             fmaf(dv, acc.y, b2l[2*b+1]));
    }
}

// ---------------- KR2: per-(b,k) sum & sumsq over PRE2, coalesced, 320 blocks ----------------
__global__ __launch_bounds__(256) void kr2(const float2* __restrict__ pre2, float* __restrict__ r2)
{
    int t = threadIdx.x;
    size_t base = (size_t)blockIdx.x * 9728;          // 320*9728 = BGR*95
    float sx[5], sy[5], qx[5], qy[5];
    #pragma unroll
    for (int b = 0; b < 5; b++) { sx[b]=0.f; sy[b]=0.f; qx[b]=0.f; qy[b]=0.f; }
    for (int n = 0; n < 38; n++) {
        size_t i = base + n*256 + t;
        float2 v = pre2[i];
        int p = (int)(i % 95);
        int b = p % 5;
        #pragma unroll
        for (int bb = 0; bb < 5; bb++) {
            bool m = (b == bb);
            sx[bb] += m ? v.x : 0.f;     sy[bb] += m ? v.y : 0.f;
            qx[bb] += m ? v.x*v.x : 0.f; qy[bb] += m ? v.y*v.y : 0.f;
        }
    }
    __shared__ float red[256][20];
    #pragma unroll
    for (int b = 0; b < 5; b++) {
        red[t][2*b] = sx[b];      red[t][2*b+1] = sy[b];
        red[t][10+2*b] = qx[b];   red[t][11+2*b] = qy[b];
    }
    __syncthreads();
    for (int off = 128; off > 0; off >>= 1) {
        if (t < off) {
            #pragma unroll
            for (int k = 0; k < 20; k++) red[t][k] += red[t+off][k];
        }
        __syncthreads();
    }
    if (t < 20) r2[blockIdx.x*20 + t] = red[0][t];
}

// ---------------- K4b: finalize BN2 stats -> A2,D2 (320 partials) ----------------
__global__ __launch_bounds__(320) void k4b(const float* __restrict__ r2,
    const float* __restrict__ g2, const float* __restrict__ bt2,
    float* __restrict__ A2, float* __restrict__ D2)
{
    __shared__ float part[16][20];
    int t = threadIdx.x;
    int col = t % 20, grp = t / 20;   // 16 groups x 20 cols
    float s = 0.f;
    for (int j = 0; j < 20; j++) s += r2[(grp*20 + j)*20 + col];
    part[grp][col] = s;
    __syncthreads();
    if (t < 20) {
        float ss = 0.f;
        #pragma unroll
        for (int j = 0; j < 16; j++) ss += part[j][t];
        part[0][t] = ss;
    }
    __syncthreads();
    if (t < 10) {
        float m = part[0][t] / (float)NTOT;
        float v = part[0][10+t] / (float)NTOT - m*m;
        float a = g2[t] * rsqrtf(v + EPS);
        A2[t] = a;
        D2[t] = bt2[t] - a*m;
    }
}

// ---------------- K4x: xc = relu(A2*pre2 + D2) in place ----------------
__global__ __launch_bounds__(256) void k4x_xc(float2* __restrict__ pre2,
    const float* __restrict__ A2, const float* __restrict__ D2)
{
    __shared__ float a2[10], d2[10];
    if (threadIdx.x < 10) { a2[threadIdx.x]=A2[threadIdx.x]; d2[threadIdx.x]=D2[threadIdx.x]; }
    __syncthreads();
    const int total = BGR*95;
    for (int i = blockIdx.x*256 + threadIdx.x; i < total; i += gridDim.x*256) {
        int p = i % 95, b = p % 5;
        float2 v = pre2[i];
        v.x = fmaxf(fmaf(a2[2*b],   v.x, d2[2*b]),   0.f);
        v.y = fmaxf(fmaf(a2[2*b+1], v.y, d2[2*b+1]), 0.f);
        pre2[i] = v;
    }
}

// ---------------- K5: pre3 = xc @ lin1_W + b (thread=feature, 16 graphs/block, permuted k) ----------------
__global__ __launch_bounds__(128) void k5_lin1(
    const float* __restrict__ xc, const float* __restrict__ W, const float* __restrict__ bias,
    float* __restrict__ pre3, float* __restrict__ p3)
{
    int bid = blockIdx.x, f = threadIdx.x;
    const float* xcb = xc + (size_t)bid*16*190;   // wave-uniform base
    float acc[16];
    #pragma unroll
    for (int r = 0; r < 16; r++) acc[r] = 0.f;
    for (int p = 0; p < 95; p++) {                // xc idx 2p (sequential), W row permuted
        int v = p/5, b = p - 5*v;
        float w0 = W[(b*38 + v*2 + 0)*128 + f];
        float w1 = W[(b*38 + v*2 + 1)*128 + f];
        #pragma unroll
        for (int r = 0; r < 16; r++) {
            float xv0 = xcb[r*190 + 2*p];
            float xv1 = xcb[r*190 + 2*p + 1];
            acc[r] = fmaf(xv1, w1, fmaf(xv0, w0, acc[r]));
        }
    }
    float bb = bias[f];
    float s = 0.f, s2 = 0.f;
    #pragma unroll
    for (int r = 0; r < 16; r++) {
        float p = acc[r] + bb;
        pre3[(size_t)(bid*16+r)*128 + f] = p;
        s += p; s2 += p*p;
    }
    p3[bid*256 + f]       = s;
    p3[bid*256 + 128 + f] = s2;
}

// ---------------- K6a/K6b: BN3 stats reduction -> affine A3,D3 ----------------
__global__ __launch_bounds__(256) void k6a(const float* __restrict__ p3, float* __restrict__ r3)
{
    int j = blockIdx.x, f = threadIdx.x;
    float s = 0.f;
    for (int r = j*32; r < (j+1)*32; r++) s += p3[r*256 + f];
    r3[j*256 + f] = s;
}

__global__ __launch_bounds__(128) void k6b(const float* __restrict__ r3,
    const float* __restrict__ g3, const float* __restrict__ bt3,
    float* __restrict__ A3, float* __restrict__ D3)
{
    int f = threadIdx.x;
    float s = 0.f, q = 0.f;
    for (int j = 0; j < 64; j++) { s += r3[j*256 + f]; q += r3[j*256 + 128 + f]; }
    float m = s / (float)BGR;
    float v = q / (float)BGR - m*m;
    float a = g3[f] * rsqrtf(v + EPS);
    A3[f] = a;
    D3[f] = bt3[f] - a*m;
}

// ---------------- K7: head, thread per graph ----------------
__global__ __launch_bounds__(256) void k7_head(
    const float* __restrict__ pre3, const float* __restrict__ A3, const float* __restrict__ D3,
    const float* __restrict__ W2h, const float* __restrict__ b2h,
    const float* __restrict__ W3h, const float* __restrict__ b3h,
    float* __restrict__ out)
{
    int g = blockIdx.x*256 + threadIdx.x;
    float accj[32];
    #pragma unroll
    for (int j = 0; j < 32; j++) accj[j] = b2h[j];
    const float* p3 = pre3 + (size_t)g*128;
    #pragma unroll 2
    for (int f4 = 0; f4 < 128; f4 += 4) {
        float4 pv = *(const float4*)(p3 + f4);
        float y0 = fmaxf(fmaf(A3[f4+0], pv.x, D3[f4+0]), 0.f);
        float y1 = fmaxf(fmaf(A3[f4+1], pv.y, D3[f4+1]), 0.f);
        float y2 = fmaxf(fmaf(A3[f4+2], pv.z, D3[f4+2]), 0.f);
        float y3 = fmaxf(fmaf(A3[f4+3], pv.w, D3[f4+3]), 0.f);
        #pragma unroll
        for (int j = 0; j < 32; j++) {
            accj[j] = fmaf(y0, W2h[(f4+0)*32+j], accj[j]);
            accj[j] = fmaf(y1, W2h[(f4+1)*32+j], accj[j]);
            accj[j] = fmaf(y2, W2h[(f4+2)*32+j], accj[j]);
            accj[j] = fmaf(y3, W2h[(f4+3)*32+j], accj[j]);
        }
    }
    float o0 = b3h[0], o1 = b3h[1];
    #pragma unroll
    for (int j = 0; j < 32; j++) {
        float yj = fmaxf(accj[j], 0.f);
        o0 = fmaf(yj, W3h[j*2+0], o0);
        o1 = fmaf(yj, W3h[j*2+1], o1);
    }
    ((float2*)out)[g] = make_float2(o0, o1);
}

extern "C" void kernel_launch(void* const* d_in, const int* in_sizes, int n_in,
                              void* d_out, int out_size, void* d_ws, size_t ws_size,
                              hipStream_t stream)
{
    (void)in_sizes; (void)n_in; (void)out_size; (void)ws_size;
    const float* x    = (const float*)d_in[0];
    const float* ew   = (const float*)d_in[1];
    const int*   eif  = (const int*)d_in[2];
    const int*   eis  = (const int*)d_in[3];
    const float* W1   = (const float*)d_in[4];
    // d_in[5] = b1: cancels exactly inside BN1 (mean subtraction) — unused
    const float* g1   = (const float*)d_in[6];
    const float* bt1  = (const float*)d_in[7];
    const float* W2   = (const float*)d_in[8];
    const float* b2   = (const float*)d_in[9];
    const float* g2   = (const float*)d_in[10];
    const float* bt2  = (const float*)d_in[11];
    const float* l1W  = (const float*)d_in[12];
    const float* l1b  = (const float*)d_in[13];
    const float* g3   = (const float*)d_in[14];
    const float* bt3  = (const float*)d_in[15];
    const float* l2W  = (const float*)d_in[16];
    const float* l2b  = (const float*)d_in[17];
    const float* l3W  = (const float*)d_in[18];
    const float* l3b  = (const float*)d_in[19];
    float* out = (float*)d_out;
    float* ws  = (float*)d_ws;

    const int* srcf = eif;  const int* dstf = eif + BGR*EF;
    const int* srcs = eis;  const int* dsts = eis + BGR*ES;

    float* U    = ws + WS_U;
    float* PRE2 = ws + WS_PRE2;
    float* PRE3 = ws + WS_PRE3;
    unsigned int* H2 = (unsigned int*)(ws + WS_H2);
    float* P3   = ws + WS_P3;
    float* R3   = ws + WS_R3;
    float* R1   = ws + WS_R1;
    float* R2   = ws + WS_R2;
    float4* T1  = (float4*)(ws + WS_T1);
    float* A2   = ws + WS_A2;
    float* D2   = ws + WS_D2;
    float* A3   = ws + WS_A3;
    float* D3   = ws + WS_D3;

    k1_gcn1<<<BGR/4, 256, 0, stream>>>(x, ew, srcf, dstf, U);
    kr1<<<160, 256, 0, stream>>>(U, R1);
    k2b<<<1, 256, 0, stream>>>(R1, W1, g1, bt1, W2, T1);
    k3a<<<(NTOT/256)*5, 256, 0, stream>>>(U, T1, H2);
    k3b<<<BGR/4, 256, 0, stream>>>(H2, srcs, dsts, b2, (float2*)PRE2);
    kr2<<<320, 256, 0, stream>>>((const float2*)PRE2, R2);
    k4b<<<1, 320, 0, stream>>>(R2, g2, bt2, A2, D2);
    k4x_xc<<<2048, 256, 0, stream>>>((float2*)PRE2, A2, D2);
    k5_lin1<<<2048, 128, 0, stream>>>(PRE2, l1W, l1b, PRE3, P3);
    k6a<<<64, 256, 0, stream>>>(P3, R3);
    k6b<<<1, 128, 0, stream>>>(R3, g3, bt3, A3, D3);
    k7_head<<<BGR/256, 256, 0, stream>>>(PRE3, A3, D3, l2W, l2b, l3W, l3b, out);
}

// Round 5
// 322.580 us; speedup vs baseline: 2.0329x; 1.1545x over previous
//
#include <hip/hip_runtime.h>
#include <hip/hip_fp16.h>

#define BGR 32768
#define NNODE 19
#define NTOT (BGR*NNODE)       // 622592
#define EF 120
#define ES 60
#define NB 5
#define EPS 1e-5f

// ---- workspace layout (float offsets) ----
#define WS_U     0                          // NTOT*NB (band-major [b][node])
#define WS_PRE2  (WS_U + NTOT*NB)           // BGR*190 (node-major [g][(v*5+b)*2+kk])
#define WS_PRE3  (WS_PRE2 + BGR*190)        // BGR*128
#define WS_H2    (WS_PRE3 + BGR*128)        // NTOT*NB uints (half2, band-major)
#define WS_P3    (WS_H2 + NTOT*NB)          // 1024*256
#define WS_R3    (WS_P3 + 2048*256)         // 64*256
#define WS_R1    (WS_R3 + 64*256)           // 160*2
#define WS_R2    (WS_R1 + 320)              // 320*20
#define WS_T1    (WS_R2 + 6400)             // 165 float4 (offset %4 == 0)
#define WS_A2    (WS_T1 + 660)              // 10
#define WS_D2    (WS_A2 + 16)               // 10
#define WS_A3    (WS_D2 + 16)               // 128
#define WS_D3    (WS_A3 + 128)              // 128

// ---------------- K1: dense-N GCN1 -> u (band-major). wave/graph, 4 graphs/block ----------------
__global__ __launch_bounds__(256) void k1_gcn1(
    const float* __restrict__ x, const float* __restrict__ ew,
    const int* __restrict__ srcf, const int* __restrict__ dstf,
    float* __restrict__ Ub)
{
    __shared__ float xg[4][96];        // x, then scaled by dinv[s] in place
    __shared__ float Nr[4][380];       // raw weighted adjacency [d][s], row pitch 20
    __shared__ float dinv[4][20];
    int t = threadIdx.x, q = t >> 6, lane = t & 63;
    int g = blockIdx.x*4 + q;

    int s0, d0, s1 = 0, d1 = 0; float w0, w1 = 0.f;
    bool e1 = (lane < EF - 64);
    s0 = srcf[g*EF+lane] - g*NNODE; d0 = dstf[g*EF+lane] - g*NNODE; w0 = ew[g*EF+lane];
    if (e1) { s1 = srcf[g*EF+lane+64] - g*NNODE; d1 = dstf[g*EF+lane+64] - g*NNODE; w1 = ew[g*EF+lane+64]; }
    for (int i = lane; i < 95; i += 64) xg[q][i] = x[g*95 + i];
    for (int i = lane; i < 380; i += 64) Nr[q][i] = 0.f;
    __syncthreads();

    atomicAdd(&Nr[q][d0*20 + s0], w0);       // one atomic per edge (random slots)
    if (e1) atomicAdd(&Nr[q][d1*20 + s1], w1);
    __syncthreads();

    if (lane < NNODE) {
        float s = 0.f;
        #pragma unroll
        for (int k = 0; k < 19; k++) s += Nr[q][lane*20 + k];
        dinv[q][lane] = rsqrtf(s + 1.f);
    }
    __syncthreads();
    for (int i = lane; i < 95; i += 64) xg[q][i] *= dinv[q][i/5];   // xg := dinv[s]*x[s][b]
    __syncthreads();

    for (int i = lane; i < 95; i += 64) {
        int b = i/19, v = i - 19*b;          // band-major output grouping
        float acc = xg[q][v*5 + b];          // self: dinv[v]^2*x = dv*(dinv[v]*x)
        #pragma unroll
        for (int s = 0; s < 19; s++) acc += Nr[q][v*20 + s] * xg[q][s*5 + b];
        Ub[(size_t)b*NTOT + g*19 + v] = dinv[q][v] * acc;
    }
}

// ---------------- KR1: (sum,sumsq) over band-major U, 160 coalesced blocks ----------------
__global__ __launch_bounds__(256) void kr1(const float* __restrict__ U, float* __restrict__ r1)
{
    const float4* base = (const float4*)(U + (size_t)blockIdx.x * (NTOT/32));   // 19456 floats
    float s = 0.f, qq = 0.f;
    for (int n = (int)threadIdx.x; n < NTOT/128; n += 256) {
        float4 v = base[n];
        s += v.x + v.y + v.z + v.w;
        qq += v.x*v.x + v.y*v.y + v.z*v.z + v.w*v.w;
    }
    __shared__ float red[256][2];
    red[threadIdx.x][0] = s; red[threadIdx.x][1] = qq;
    __syncthreads();
    for (int off = 128; off > 0; off >>= 1) {
        if ((int)threadIdx.x < off) {
            red[threadIdx.x][0] += red[threadIdx.x+off][0];
            red[threadIdx.x][1] += red[threadIdx.x+off][1];
        }
        __syncthreads();
    }
    if (threadIdx.x < 2) r1[blockIdx.x*2 + threadIdx.x] = red[0][threadIdx.x];
}

// ---------------- K2b: BN1 stats -> packed padded table T1[b][33] = (A1,D1,W2_0,W2_1) ----------------
__global__ __launch_bounds__(256) void k2b(const float* __restrict__ r1,
    const float* __restrict__ W1, const float* __restrict__ g1, const float* __restrict__ bt1,
    const float* __restrict__ W2, float4* __restrict__ T1)
{
    __shared__ float mean[5], varr[5];
    int t = threadIdx.x;
    if (t < 5) {
        float s = 0.f, qq = 0.f;
        for (int j = 0; j < 32; j++) { s += r1[(t*32+j)*2]; qq += r1[(t*32+j)*2+1]; }
        float m = s / (float)NTOT;
        mean[t] = m;
        varr[t] = qq / (float)NTOT - m*m;
    }
    __syncthreads();
    if (t < 160) {
        int b = t >> 5;
        float w = W1[t];
        float c = w * rsqrtf(w*w*varr[b] + EPS) * g1[t];
        T1[b*33 + (t & 31)] = make_float4(c, bt1[t] - c*mean[b], W2[t*2], W2[t*2+1]);
    }
}

// ---------------- K3a: dense h2 map, band-uniform block, fully coalesced ----------------
__global__ __launch_bounds__(256) void k3a(
    const float* __restrict__ Ub, const float4* __restrict__ T1p,
    unsigned int* __restrict__ H2)
{
    int bb = blockIdx.x / (NTOT/256);                 // block-uniform band -> s_loads
    int node = (blockIdx.x - bb*(NTOT/256))*256 + (int)threadIdx.x;
    float uv = Ub[(size_t)bb*NTOT + node];            // coalesced
    const float4* Tb = T1p + bb*33;
    float hx = 0.f, hy = 0.f;
    #pragma unroll
    for (int f = 0; f < 32; f++) {
        float4 c = Tb[f];                             // wave-uniform scalar loads
        float r = fmaxf(fmaf(c.x, uv, c.y), 0.f);
        hx = fmaf(r, c.z, hx);
        hy = fmaf(r, c.w, hy);
    }
    __half2 h = __floats2half2_rn(hx, hy);
    H2[(size_t)bb*NTOT + node] = *(unsigned int*)&h;  // coalesced
}

// ---------------- K3b: dense-M GCN2 aggregate. wave/graph, 4 graphs/block ----------------
__global__ __launch_bounds__(256) void k3b(
    const unsigned int* __restrict__ H2, const int* __restrict__ srcs, const int* __restrict__ dsts,
    const float* __restrict__ b2, float2* __restrict__ pre2)
{
    __shared__ float2 h2l[4][96];      // [s*5+b], pre-scaled by dinv[s]
    __shared__ float  Mr[4][380];      // struct adjacency counts [d][s], pitch 20
    __shared__ float  dinv[4][20];
    __shared__ float  b2l[12];
    int t = threadIdx.x, q = t >> 6, lane = t & 63;
    int g = blockIdx.x*4 + q;

    int b0 = lane/19, v0 = lane - 19*b0;
    unsigned int h0 = H2[(size_t)b0*NTOT + g*19 + v0];
    int b1 = (lane+64)/19, v1 = (lane+64) - 19*b1;
    unsigned int h1 = (lane < 31) ? H2[(size_t)b1*NTOT + g*19 + v1] : 0u;
    int ls = 0, ld = 0; bool ee = (lane < ES);
    if (ee) { ls = srcs[g*ES+lane] - g*NNODE; ld = dsts[g*ES+lane] - g*NNODE; }
    if (t < 10) b2l[t] = b2[t];
    for (int i = lane; i < 380; i += 64) Mr[q][i] = 0.f;
    __syncthreads();

    if (ee) atomicAdd(&Mr[q][ld*20 + ls], 1.f);
    __syncthreads();

    if (lane < NNODE) {
        float s = 0.f;
        #pragma unroll
        for (int k = 0; k < 19; k++) s += Mr[q][lane*20 + k];
        dinv[q][lane] = rsqrtf(s + 1.f);
    }
    __syncthreads();

    {
        float2 f0 = __half22float2(*(__half2*)&h0);
        float sc = dinv[q][v0];
        h2l[q][v0*5 + b0] = make_float2(f0.x*sc, f0.y*sc);
        if (lane < 31) {
            float2 f1 = __half22float2(*(__half2*)&h1);
            float sc1 = dinv[q][v1];
            h2l[q][v1*5 + b1] = make_float2(f1.x*sc1, f1.y*sc1);
        }
    }
    __syncthreads();

    for (int i = lane; i < 95; i += 64) {
        int v = i/5, b = i - 5*v;
        float2 acc = h2l[q][i];                       // self term
        #pragma unroll
        for (int s = 0; s < 19; s++) {
            float m = Mr[q][v*20 + s];
            float2 hh = h2l[q][s*5 + b];
            acc.x = fmaf(m, hh.x, acc.x);
            acc.y = fmaf(m, hh.y, acc.y);
        }
        float dv = dinv[q][v];
        pre2[(size_t)g*95 + i] = make_float2(fmaf(dv, acc.x, b2l[2*b]),
                                             fmaf(dv, acc.y, b2l[2*b+1]));
    }
}

// ---------------- KR2: per-(b,k) sum & sumsq over PRE2, coalesced, 320 blocks ----------------
__global__ __launch_bounds__(256) void kr2(const float2* __restrict__ pre2, float* __restrict__ r2)
{
    int t = threadIdx.x;
    size_t base = (size_t)blockIdx.x * 9728;          // 320*9728 = BGR*95
    float sx[5], sy[5], qx[5], qy[5];
    #pragma unroll
    for (int b = 0; b < 5; b++) { sx[b]=0.f; sy[b]=0.f; qx[b]=0.f; qy[b]=0.f; }
    for (int n = 0; n < 38; n++) {
        size_t i = base + n*256 + t;
        float2 v = pre2[i];
        int p = (int)(i % 95);
        int b = p % 5;
        #pragma unroll
        for (int bb = 0; bb < 5; bb++) {
            bool m = (b == bb);
            sx[bb] += m ? v.x : 0.f;     sy[bb] += m ? v.y : 0.f;
            qx[bb] += m ? v.x*v.x : 0.f; qy[bb] += m ? v.y*v.y : 0.f;
        }
    }
    __shared__ float red[256][20];
    #pragma unroll
    for (int b = 0; b < 5; b++) {
        red[t][2*b] = sx[b];      red[t][2*b+1] = sy[b];
        red[t][10+2*b] = qx[b];   red[t][11+2*b] = qy[b];
    }
    __syncthreads();
    for (int off = 128; off > 0; off >>= 1) {
        if (t < off) {
            #pragma unroll
            for (int k = 0; k < 20; k++) red[t][k] += red[t+off][k];
        }
        __syncthreads();
    }
    if (t < 20) r2[blockIdx.x*20 + t] = red[0][t];
}

// ---------------- K4b: finalize BN2 stats -> A2,D2 (320 partials) ----------------
__global__ __launch_bounds__(320) void k4b(const float* __restrict__ r2,
    const float* __restrict__ g2, const float* __restrict__ bt2,
    float* __restrict__ A2, float* __restrict__ D2)
{
    __shared__ float part[16][20];
    int t = threadIdx.x;
    int col = t % 20, grp = t / 20;   // 16 groups x 20 cols
    float s = 0.f;
    for (int j = 0; j < 20; j++) s += r2[(grp*20 + j)*20 + col];
    part[grp][col] = s;
    __syncthreads();
    if (t < 20) {
        float ss = 0.f;
        #pragma unroll
        for (int j = 0; j < 16; j++) ss += part[j][t];
        part[0][t] = ss;
    }
    __syncthreads();
    if (t < 10) {
        float m = part[0][t] / (float)NTOT;
        float v = part[0][10+t] / (float)NTOT - m*m;
        float a = g2[t] * rsqrtf(v + EPS);
        A2[t] = a;
        D2[t] = bt2[t] - a*m;
    }
}

// ---------------- K5: pre3 = relu(BN2(pre2)) @ lin1_W + b. 32 graphs x 128 feats per block ----------------
// BN2-affine fused into LDS staging (replaces old k4x pass).
__global__ __launch_bounds__(256) void k5_lin1(
    const float2* __restrict__ pre2, const float* __restrict__ A2, const float* __restrict__ D2,
    const float* __restrict__ W, const float* __restrict__ bias,
    float* __restrict__ pre3, float* __restrict__ p3)
{
    __shared__ float xg[32*192];       // 24.6 KB, k-padded to 192
    __shared__ float a2l[10], d2l[10];
    __shared__ float redS[4][128], redQ[4][128];
    int t = threadIdx.x, bid = blockIdx.x;
    if (t < 10) { a2l[t] = A2[t]; d2l[t] = D2[t]; }
    if (t < 64) xg[(t>>1)*192 + 190 + (t&1)] = 0.f;   // zero the k-pad
    __syncthreads();

    const float2* src = pre2 + (size_t)bid*3040;      // 32 graphs * 95 float2
    for (int i = t; i < 3040; i += 256) {
        int gg = i / 95, p = i - gg*95;
        int b = p % 5;
        float2 v = src[i];
        xg[gg*192 + 2*p]     = fmaxf(fmaf(a2l[2*b],   v.x, d2l[2*b]),   0.f);
        xg[gg*192 + 2*p + 1] = fmaxf(fmaf(a2l[2*b+1], v.y, d2l[2*b+1]), 0.f);
    }
    __syncthreads();

    int f = t & 63, h = t >> 6;        // wave h owns graphs 8h..8h+7; lane f -> feats f, f+64
    const float* xh = xg + h*8*192;
    float accA[8], accB[8];
    #pragma unroll
    for (int r = 0; r < 8; r++) { accA[r] = 0.f; accB[r] = 0.f; }

    for (int kt = 0; kt < 12; kt++) {
        float wA[16], wB[16];
        #pragma unroll
        for (int j = 0; j < 16; j++) {
            int k = kt*16 + j;
            if (k < 190) {
                int p = k >> 1, kk = k & 1;
                int v = p/5, b = p - 5*v;
                int row = b*38 + v*2 + kk;         // W row permutation to xc's k-order
                wA[j] = W[row*128 + f];
                wB[j] = W[row*128 + f + 64];
            } else { wA[j] = 0.f; wB[j] = 0.f; }
        }
        #pragma unroll
        for (int r = 0; r < 8; r++) {
            const float4* xr = (const float4*)(xh + r*192 + kt*16);
            #pragma unroll
            for (int jj = 0; jj < 4; jj++) {
                float4 xv = xr[jj];
                accA[r] = fmaf(xv.x, wA[4*jj+0], accA[r]);
                accA[r] = fmaf(xv.y, wA[4*jj+1], accA[r]);
                accA[r] = fmaf(xv.z, wA[4*jj+2], accA[r]);
                accA[r] = fmaf(xv.w, wA[4*jj+3], accA[r]);
                accB[r] = fmaf(xv.x, wB[4*jj+0], accB[r]);
                accB[r] = fmaf(xv.y, wB[4*jj+1], accB[r]);
                accB[r] = fmaf(xv.z, wB[4*jj+2], accB[r]);
                accB[r] = fmaf(xv.w, wB[4*jj+3], accB[r]);
            }
        }
    }

    float bb0 = bias[f], bb1 = bias[f + 64];
    float sA = 0.f, qA = 0.f, sB = 0.f, qB = 0.f;
    int g0 = bid*32 + h*8;
    #pragma unroll
    for (int r = 0; r < 8; r++) {
        float pA = accA[r] + bb0;
        float pB = accB[r] + bb1;
        pre3[(size_t)(g0+r)*128 + f]      = pA;
        pre3[(size_t)(g0+r)*128 + f + 64] = pB;
        sA += pA; qA += pA*pA;
        sB += pB; qB += pB*pB;
    }
    redS[h][f] = sA; redS[h][f+64] = sB;
    redQ[h][f] = qA; redQ[h][f+64] = qB;
    __syncthreads();
    if (t < 128) {
        p3[bid*256 + t] = redS[0][t] + redS[1][t] + redS[2][t] + redS[3][t];
    } else {
        int f2 = t - 128;
        p3[bid*256 + 128 + f2] = redQ[0][f2] + redQ[1][f2] + redQ[2][f2] + redQ[3][f2];
    }
}

// ---------------- K6a/K6b: BN3 stats reduction -> affine A3,D3 ----------------
__global__ __launch_bounds__(256) void k6a(const float* __restrict__ p3, float* __restrict__ r3)
{
    int j = blockIdx.x, f = threadIdx.x;
    float s = 0.f;
    for (int r = j*16; r < (j+1)*16; r++) s += p3[r*256 + f];   // 1024 rows / 64 blocks
    r3[j*256 + f] = s;
}

__global__ __launch_bounds__(128) void k6b(const float* __restrict__ r3,
    const float* __restrict__ g3, const float* __restrict__ bt3,
    float* __restrict__ A3, float* __restrict__ D3)
{
    int f = threadIdx.x;
    float s = 0.f, q = 0.f;
    for (int j = 0; j < 64; j++) { s += r3[j*256 + f]; q += r3[j*256 + 128 + f]; }
    float m = s / (float)BGR;
    float v = q / (float)BGR - m*m;
    float a = g3[f] * rsqrtf(v + EPS);
    A3[f] = a;
    D3[f] = bt3[f] - a*m;
}

// ---------------- K7: head, thread per graph ----------------
__global__ __launch_bounds__(256) void k7_head(
    const float* __restrict__ pre3, const float* __restrict__ A3, const float* __restrict__ D3,
    const float* __restrict__ W2h, const float* __restrict__ b2h,
    const float* __restrict__ W3h, const float* __restrict__ b3h,
    float* __restrict__ out)
{
    int g = blockIdx.x*256 + threadIdx.x;
    float accj[32];
    #pragma unroll
    for (int j = 0; j < 32; j++) accj[j] = b2h[j];
    const float* p3 = pre3 + (size_t)g*128;
    #pragma unroll 2
    for (int f4 = 0; f4 < 128; f4 += 4) {
        float4 pv = *(const float4*)(p3 + f4);
        float y0 = fmaxf(fmaf(A3[f4+0], pv.x, D3[f4+0]), 0.f);
        float y1 = fmaxf(fmaf(A3[f4+1], pv.y, D3[f4+1]), 0.f);
        float y2 = fmaxf(fmaf(A3[f4+2], pv.z, D3[f4+2]), 0.f);
        float y3 = fmaxf(fmaf(A3[f4+3], pv.w, D3[f4+3]), 0.f);
        #pragma unroll
        for (int j = 0; j < 32; j++) {
            accj[j] = fmaf(y0, W2h[(f4+0)*32+j], accj[j]);
            accj[j] = fmaf(y1, W2h[(f4+1)*32+j], accj[j]);
            accj[j] = fmaf(y2, W2h[(f4+2)*32+j], accj[j]);
            accj[j] = fmaf(y3, W2h[(f4+3)*32+j], accj[j]);
        }
    }
    float o0 = b3h[0], o1 = b3h[1];
    #pragma unroll
    for (int j = 0; j < 32; j++) {
        float yj = fmaxf(accj[j], 0.f);
        o0 = fmaf(yj, W3h[j*2+0], o0);
        o1 = fmaf(yj, W3h[j*2+1], o1);
    }
    ((float2*)out)[g] = make_float2(o0, o1);
}

extern "C" void kernel_launch(void* const* d_in, const int* in_sizes, int n_in,
                              void* d_out, int out_size, void* d_ws, size_t ws_size,
                              hipStream_t stream)
{
    (void)in_sizes; (void)n_in; (void)out_size; (void)ws_size;
    const float* x    = (const float*)d_in[0];
    const float* ew   = (const float*)d_in[1];
    const int*   eif  = (const int*)d_in[2];
    const int*   eis  = (const int*)d_in[3];
    const float* W1   = (const float*)d_in[4];
    // d_in[5] = b1: cancels exactly inside BN1 (mean subtraction) — unused
    const float* g1   = (const float*)d_in[6];
    const float* bt1  = (const float*)d_in[7];
    const float* W2   = (const float*)d_in[8];
    const float* b2   = (const float*)d_in[9];
    const float* g2   = (const float*)d_in[10];
    const float* bt2  = (const float*)d_in[11];
    const float* l1W  = (const float*)d_in[12];
    const float* l1b  = (const float*)d_in[13];
    const float* g3   = (const float*)d_in[14];
    const float* bt3  = (const float*)d_in[15];
    const float* l2W  = (const float*)d_in[16];
    const float* l2b  = (const float*)d_in[17];
    const float* l3W  = (const float*)d_in[18];
    const float* l3b  = (const float*)d_in[19];
    float* out = (float*)d_out;
    float* ws  = (float*)d_ws;

    const int* srcf = eif;  const int* dstf = eif + BGR*EF;
    const int* srcs = eis;  const int* dsts = eis + BGR*ES;

    float* U    = ws + WS_U;
    float* PRE2 = ws + WS_PRE2;
    float* PRE3 = ws + WS_PRE3;
    unsigned int* H2 = (unsigned int*)(ws + WS_H2);
    float* P3   = ws + WS_P3;
    float* R3   = ws + WS_R3;
    float* R1   = ws + WS_R1;
    float* R2   = ws + WS_R2;
    float4* T1  = (float4*)(ws + WS_T1);
    float* A2   = ws + WS_A2;
    float* D2   = ws + WS_D2;
    float* A3   = ws + WS_A3;
    float* D3   = ws + WS_D3;

    k1_gcn1<<<BGR/4, 256, 0, stream>>>(x, ew, srcf, dstf, U);
    kr1<<<160, 256, 0, stream>>>(U, R1);
    k2b<<<1, 256, 0, stream>>>(R1, W1, g1, bt1, W2, T1);
    k3a<<<(NTOT/256)*5, 256, 0, stream>>>(U, T1, H2);
    k3b<<<BGR/4, 256, 0, stream>>>(H2, srcs, dsts, b2, (float2*)PRE2);
    kr2<<<320, 256, 0, stream>>>((const float2*)PRE2, R2);
    k4b<<<1, 320, 0, stream>>>(R2, g2, bt2, A2, D2);
    k5_lin1<<<1024, 256, 0, stream>>>((const float2*)PRE2, A2, D2, l1W, l1b, PRE3, P3);
    k6a<<<64, 256, 0, stream>>>(P3, R3);
    k6b<<<1, 128, 0, stream>>>(R3, g3, bt3, A3, D3);
    k7_head<<<BGR/256, 256, 0, stream>>>(PRE3, A3, D3, l2W, l2b, l3W, l3b, out);
}